// Round 5
// baseline (461.820 us; speedup 1.0000x reference)
//
#include <hip/hip_runtime.h>

#define N_NODES   100352
#define N_EDGES   1605632
#define IN_C      128
#define HID_C     64
#define OUT_C     32
#define NUM_GRAPHS 512
#define NPG       196
#define TOPK      30

// ws layout (bytes)
#define OFF_DEG     0u          // int[N]
#define OFF_ROWPTR  401408u     // int[N]
#define OFF_FILL    802816u     // int[N]
#define OFF_BSUM    1204224u    // int[98]
#define OFF_BOFF    1204736u    // int[98]
#define OFF_DIS     1205248u    // float[N]
#define OFF_CSR     1606656u    // int[E]
#define OFF_XW1     8029184u    // float[N*64]  (dis-scaled)
#define OFF_H       33719296u   // float[N*64]
#define OFF_XW2     59409408u   // float[N*32]  (dis-scaled)
#define OFF_OUT2    72254464u   // float[N*32]
// total: ~85 MB

// 4 edges per thread: independent atomics overlap their ~800-cyc latency.
__global__ void k_deg(const int* __restrict__ dst, int* __restrict__ deg) {
    int i = blockIdx.x * blockDim.x + threadIdx.x;   // i < N_EDGES/4
    int4 d = ((const int4*)dst)[i];
    atomicAdd(&deg[d.x], 1);
    atomicAdd(&deg[d.y], 1);
    atomicAdd(&deg[d.z], 1);
    atomicAdd(&deg[d.w], 1);
}

__global__ __launch_bounds__(1024) void k_bsum(const int* __restrict__ deg, int* __restrict__ bsum) {
    __shared__ int s[1024];
    int t = threadIdx.x;
    s[t] = deg[blockIdx.x * 1024 + t];
    __syncthreads();
    for (int o = 512; o > 0; o >>= 1) {
        if (t < o) s[t] += s[t + o];
        __syncthreads();
    }
    if (t == 0) bsum[blockIdx.x] = s[0];
}

__global__ void k_bscan(const int* __restrict__ bsum, int* __restrict__ boff) {
    if (threadIdx.x == 0) {
        int run = 0;
        for (int b = 0; b < 98; ++b) { boff[b] = run; run += bsum[b]; }
    }
}

__global__ __launch_bounds__(1024) void k_scan(const int* __restrict__ deg, const int* __restrict__ boff,
                                               int* __restrict__ row_ptr, int* __restrict__ fill_pos,
                                               float* __restrict__ dis) {
    __shared__ int s[1024];
    int t = threadIdx.x;
    int i = blockIdx.x * 1024 + t;
    int v = deg[i];
    s[t] = v;
    __syncthreads();
    for (int o = 1; o < 1024; o <<= 1) {
        int a = (t >= o) ? s[t - o] : 0;
        __syncthreads();
        s[t] += a;
        __syncthreads();
    }
    int start = boff[blockIdx.x] + s[t] - v;   // exclusive prefix
    row_ptr[i] = start;
    fill_pos[i] = start;
    dis[i] = (float)(1.0 / sqrt((double)(v + 1)));   // +1 self-loop
}

// 4 edges per thread: 4 independent atomic+store chains in flight.
__global__ void k_fill(const int* __restrict__ src, const int* __restrict__ dst,
                       int* __restrict__ fill_pos, int* __restrict__ csr_src) {
    int i = blockIdx.x * blockDim.x + threadIdx.x;   // i < N_EDGES/4
    int4 s = ((const int4*)src)[i];
    int4 d = ((const int4*)dst)[i];
    int p0 = atomicAdd(&fill_pos[d.x], 1);
    int p1 = atomicAdd(&fill_pos[d.y], 1);
    int p2 = atomicAdd(&fill_pos[d.z], 1);
    int p3 = atomicAdd(&fill_pos[d.w], 1);
    csr_src[p0] = s.x;
    csr_src[p1] = s.y;
    csr_src[p2] = s.z;
    csr_src[p3] = s.w;
}

// xw1s = dis[n] * (x @ W1). W1 in LDS; lane = col; 8 nodes in flight per thread.
#define MM1_NPW 8
__global__ __launch_bounds__(256) void k_mm1(const float* __restrict__ x, const float* __restrict__ W1,
                                             const float* __restrict__ dis, float* __restrict__ xw1s) {
    __shared__ float wlds[IN_C * HID_C];   // 32 KB
    int tid = threadIdx.x;
    for (int i = tid; i < IN_C * HID_C / 4; i += 256)
        ((float4*)wlds)[i] = ((const float4*)W1)[i];
    __syncthreads();
    int lane = tid & 63;
    int wid = blockIdx.x * 4 + (tid >> 6);
    int n0 = wid * MM1_NPW;
    const float* xb = x + (size_t)n0 * IN_C;
    float acc[MM1_NPW] = {0.f, 0.f, 0.f, 0.f, 0.f, 0.f, 0.f, 0.f};
#pragma unroll 4
    for (int q = 0; q < IN_C / 4; ++q) {
        float4 xv[MM1_NPW];
#pragma unroll
        for (int j = 0; j < MM1_NPW; ++j)
            xv[j] = *(const float4*)(xb + j * IN_C + 4 * q);   // wave-uniform -> broadcast
#pragma unroll
        for (int kk = 0; kk < 4; ++kk) {
            float wv = wlds[(4 * q + kk) * HID_C + lane];       // LDS: runtime index is fine
#pragma unroll
            for (int j = 0; j < MM1_NPW; ++j) {
                float xs = (kk == 0) ? xv[j].x : (kk == 1) ? xv[j].y : (kk == 2) ? xv[j].z : xv[j].w;
                acc[j] = fmaf(xs, wv, acc[j]);
            }
        }
    }
#pragma unroll
    for (int j = 0; j < MM1_NPW; ++j)
        xw1s[(size_t)(n0 + j) * HID_C + lane] = acc[j] * dis[n0 + j];
}

// layer-1 aggregation: one 64-lane wave per node; dis folded; 8 gather loads in flight.
__global__ __launch_bounds__(256) void k_agg1(const float* __restrict__ xw1s, const int* __restrict__ csr_src,
                                              const int* __restrict__ row_ptr, const int* __restrict__ deg,
                                              const float* __restrict__ dis, const float* __restrict__ b1,
                                              float* __restrict__ h) {
    int lane = threadIdx.x & 63;
    int v = blockIdx.x * 4 + (threadIdx.x >> 6);
    int start = row_ptr[v];
    int cnt = deg[v];
    float acc0 = xw1s[(size_t)v * HID_C + lane];   // self-loop term (already dis-scaled)
    float acc1 = 0.f, acc2 = 0.f, acc3 = 0.f;
    for (int base = 0; base < cnt; base += 64) {
        int mcnt = min(64, cnt - base);
        int sj = 0;
        if (lane < mcnt) sj = csr_src[start + base + lane];
        int j = 0;
        for (; j + 8 <= mcnt; j += 8) {
            int s0 = __shfl(sj, j + 0), s1 = __shfl(sj, j + 1);
            int s2 = __shfl(sj, j + 2), s3 = __shfl(sj, j + 3);
            int s4 = __shfl(sj, j + 4), s5 = __shfl(sj, j + 5);
            int s6 = __shfl(sj, j + 6), s7 = __shfl(sj, j + 7);
            float v0 = xw1s[(size_t)s0 * HID_C + lane];
            float v1 = xw1s[(size_t)s1 * HID_C + lane];
            float v2 = xw1s[(size_t)s2 * HID_C + lane];
            float v3 = xw1s[(size_t)s3 * HID_C + lane];
            float v4 = xw1s[(size_t)s4 * HID_C + lane];
            float v5 = xw1s[(size_t)s5 * HID_C + lane];
            float v6 = xw1s[(size_t)s6 * HID_C + lane];
            float v7 = xw1s[(size_t)s7 * HID_C + lane];
            acc0 += v0 + v4;
            acc1 += v1 + v5;
            acc2 += v2 + v6;
            acc3 += v3 + v7;
        }
        for (; j < mcnt; ++j) {
            int s = __shfl(sj, j);
            acc0 += xw1s[(size_t)s * HID_C + lane];
        }
    }
    float o = fmaf(dis[v], (acc0 + acc1) + (acc2 + acc3), b1[lane]);
    h[(size_t)v * HID_C + lane] = fmaxf(o, 0.f);   // ReLU fused
}

// xw2s = dis[n] * (h @ W2). W2 in LDS; half-wave = node slot; 8 nodes per half-wave.
#define MM2_NPW 8
__global__ __launch_bounds__(256) void k_mm2(const float* __restrict__ h, const float* __restrict__ W2,
                                             const float* __restrict__ dis, float* __restrict__ xw2s) {
    __shared__ float wlds[HID_C * OUT_C];   // 8 KB
    int tid = threadIdx.x;
    for (int i = tid; i < HID_C * OUT_C / 4; i += 256)
        ((float4*)wlds)[i] = ((const float4*)W2)[i];
    __syncthreads();
    int lane = tid & 63;
    int c = lane & 31;
    int half = lane >> 5;
    int wid = blockIdx.x * 4 + (tid >> 6);
    int n0 = wid * 2 * MM2_NPW;             // 16 nodes per wave
    const float* hb = h + (size_t)(n0 + half) * HID_C;
    float acc[MM2_NPW] = {0.f, 0.f, 0.f, 0.f, 0.f, 0.f, 0.f, 0.f};
#pragma unroll 4
    for (int q = 0; q < HID_C / 4; ++q) {
        float4 xv[MM2_NPW];
#pragma unroll
        for (int j = 0; j < MM2_NPW; ++j)
            xv[j] = *(const float4*)(hb + (size_t)(2 * j) * HID_C + 4 * q);
#pragma unroll
        for (int kk = 0; kk < 4; ++kk) {
            float wv = wlds[(4 * q + kk) * OUT_C + c];
#pragma unroll
            for (int j = 0; j < MM2_NPW; ++j) {
                float xs = (kk == 0) ? xv[j].x : (kk == 1) ? xv[j].y : (kk == 2) ? xv[j].z : xv[j].w;
                acc[j] = fmaf(xs, wv, acc[j]);
            }
        }
    }
#pragma unroll
    for (int j = 0; j < MM2_NPW; ++j) {
        int n = n0 + 2 * j + half;
        xw2s[(size_t)n * OUT_C + c] = acc[j] * dis[n];
    }
}

// layer-2 aggregation: 32-lane group per node; dis folded; 8 gather loads in flight.
__global__ __launch_bounds__(256) void k_agg2(const float* __restrict__ xw2s, const int* __restrict__ csr_src,
                                              const int* __restrict__ row_ptr, const int* __restrict__ deg,
                                              const float* __restrict__ dis, const float* __restrict__ b2,
                                              float* __restrict__ out2) {
    int lane = threadIdx.x & 31;
    int v = blockIdx.x * 8 + (threadIdx.x >> 5);
    int start = row_ptr[v];
    int cnt = deg[v];
    float acc0 = xw2s[(size_t)v * OUT_C + lane];   // self-loop term
    float acc1 = 0.f, acc2 = 0.f, acc3 = 0.f;
    for (int base = 0; base < cnt; base += 32) {
        int mcnt = min(32, cnt - base);
        int sj = 0;
        if (lane < mcnt) sj = csr_src[start + base + lane];
        int j = 0;
        for (; j + 8 <= mcnt; j += 8) {
            int s0 = __shfl(sj, j + 0, 32), s1 = __shfl(sj, j + 1, 32);
            int s2 = __shfl(sj, j + 2, 32), s3 = __shfl(sj, j + 3, 32);
            int s4 = __shfl(sj, j + 4, 32), s5 = __shfl(sj, j + 5, 32);
            int s6 = __shfl(sj, j + 6, 32), s7 = __shfl(sj, j + 7, 32);
            float v0 = xw2s[(size_t)s0 * OUT_C + lane];
            float v1 = xw2s[(size_t)s1 * OUT_C + lane];
            float v2 = xw2s[(size_t)s2 * OUT_C + lane];
            float v3 = xw2s[(size_t)s3 * OUT_C + lane];
            float v4 = xw2s[(size_t)s4 * OUT_C + lane];
            float v5 = xw2s[(size_t)s5 * OUT_C + lane];
            float v6 = xw2s[(size_t)s6 * OUT_C + lane];
            float v7 = xw2s[(size_t)s7 * OUT_C + lane];
            acc0 += v0 + v4;
            acc1 += v1 + v5;
            acc2 += v2 + v6;
            acc3 += v3 + v7;
        }
        for (; j < mcnt; ++j) {
            int s = __shfl(sj, j, 32);
            acc0 += xw2s[(size_t)s * OUT_C + lane];
        }
    }
    out2[(size_t)v * OUT_C + lane] = fmaf(dis[v], (acc0 + acc1) + (acc2 + acc3), b2[lane]);
}

// per-graph top-30 by channel 31 (desc, stable), emit [512, 30*32] f32.
__global__ __launch_bounds__(256) void k_sort(const float* __restrict__ out2, float* __restrict__ out) {
    __shared__ float keys[NPG];
    __shared__ int order[TOPK];
    int g = blockIdx.x;
    int tid = threadIdx.x;
    int base = g * NPG;
    if (tid < NPG) keys[tid] = out2[(size_t)(base + tid) * OUT_C + (OUT_C - 1)];
    __syncthreads();
    if (tid < NPG) {
        float my = keys[tid];
        int r = 0;
        for (int j = 0; j < NPG; ++j) {
            float kj = keys[j];
            r += (kj > my) || (kj == my && j < tid);
        }
        if (r < TOPK) order[r] = tid;
    }
    __syncthreads();
    for (int idx = tid; idx < TOPK * OUT_C; idx += 256) {
        int r = idx >> 5;
        int c = idx & 31;
        int n = order[r];
        out[g * (TOPK * OUT_C) + idx] = out2[(size_t)(base + n) * OUT_C + c];
    }
}

extern "C" void kernel_launch(void* const* d_in, const int* in_sizes, int n_in,
                              void* d_out, int out_size, void* d_ws, size_t ws_size,
                              hipStream_t stream) {
    const float* x  = (const float*)d_in[0];
    const int*   ei = (const int*)d_in[1];
    const int*   srcp = ei;             // edge_index[0]
    const int*   dstp = ei + N_EDGES;   // edge_index[1]
    // d_in[2] (batch) unused: graphs are contiguous 196-node blocks.
    const float* W1 = (const float*)d_in[3];
    const float* b1 = (const float*)d_in[4];
    const float* W2 = (const float*)d_in[5];
    const float* b2 = (const float*)d_in[6];
    float* out = (float*)d_out;

    char* w = (char*)d_ws;
    int*    deg      = (int*)(w + OFF_DEG);
    int*    row_ptr  = (int*)(w + OFF_ROWPTR);
    int*    fill_pos = (int*)(w + OFF_FILL);
    int*    bsum     = (int*)(w + OFF_BSUM);
    int*    boff     = (int*)(w + OFF_BOFF);
    float*  dis      = (float*)(w + OFF_DIS);
    int*    csr_src  = (int*)(w + OFF_CSR);
    float*  xw1s     = (float*)(w + OFF_XW1);
    float*  h        = (float*)(w + OFF_H);
    float*  xw2s     = (float*)(w + OFF_XW2);
    float*  out2     = (float*)(w + OFF_OUT2);

    hipMemsetAsync(deg, 0, N_NODES * sizeof(int), stream);
    k_deg  <<<N_EDGES / 4 / 256, 256, 0, stream>>>(dstp, deg);
    k_bsum <<<98, 1024, 0, stream>>>(deg, bsum);
    k_bscan<<<1, 64, 0, stream>>>(bsum, boff);
    k_scan <<<98, 1024, 0, stream>>>(deg, boff, row_ptr, fill_pos, dis);
    k_fill <<<N_EDGES / 4 / 256, 256, 0, stream>>>(srcp, dstp, fill_pos, csr_src);
    k_mm1  <<<N_NODES / (MM1_NPW * 4), 256, 0, stream>>>(x, W1, dis, xw1s);
    k_agg1 <<<N_NODES / 4, 256, 0, stream>>>(xw1s, csr_src, row_ptr, deg, dis, b1, h);
    k_mm2  <<<N_NODES / (MM2_NPW * 2 * 4), 256, 0, stream>>>(h, W2, dis, xw2s);
    k_agg2 <<<N_NODES / 8, 256, 0, stream>>>(xw2s, csr_src, row_ptr, deg, dis, b2, out2);
    k_sort <<<NUM_GRAPHS, 256, 0, stream>>>(out2, out);
}

// Round 6
// 295.183 us; speedup vs baseline: 1.5645x; 1.5645x over previous
//
#include <hip/hip_runtime.h>

#define N_NODES   100352
#define N_EDGES   1605632
#define IN_C      128
#define HID_C     64
#define OUT_C     32
#define NUM_GRAPHS 512
#define NPG       196
#define TOPK      30

#define NB        196     // buckets = dst>>9 (512 nodes each; 196*512 = 100352)
#define BCAP      10240   // arena capacity per bucket (E[nb]=8192, sigma~90)
#define LCAP      10240   // LDS staging capacity in k_build (40 KB)

// ws layout (bytes)
#define OFF_DEG     0u          // int[N]
#define OFF_ROWPTR  401408u     // int[N]
#define OFF_DIS     802816u     // float[N]
#define OFF_BCNT    1204224u    // int[NB]
#define OFF_BBASE   1205248u    // int[NB]
#define OFF_ARENA   1206272u    // int2[NB*BCAP] = 16,056,320 B  (dead after k_build)
#define OFF_OUT2    1206272u    // float[N*32] = 12,845,056 B  -- aliases arena
#define OFF_CSR     17262592u   // int[E]
#define OFF_XW1     23685120u   // float[N*64]  (dis-scaled)
#define OFF_H       49375232u   // float[N*64]
#define OFF_XW2     75065344u   // float[N*32]  (dis-scaled)
// total: 87,910,400 + 12,845,056 = 87.9 MB

// Pass 1: bucketize edges. LDS histogram -> one global atomic per (block,bucket)
// -> writes to 196 sequential arena windows (sectors fill -> no write amplification).
__global__ __launch_bounds__(256) void k_bucket(const int* __restrict__ src, const int* __restrict__ dst,
                                                int* __restrict__ bucket_cnt, int2* __restrict__ arena) {
    __shared__ int hist[NB];
    __shared__ int cur[NB];
    int tid = threadIdx.x;
    for (int i = tid; i < NB; i += 256) hist[i] = 0;
    __syncthreads();
    int e0 = (blockIdx.x * 256 + tid) * 8;       // 8 edges per thread
    int4 sa = ((const int4*)src)[e0 / 4], sb = ((const int4*)src)[e0 / 4 + 1];
    int4 da = ((const int4*)dst)[e0 / 4], db = ((const int4*)dst)[e0 / 4 + 1];
    int es[8] = {sa.x, sa.y, sa.z, sa.w, sb.x, sb.y, sb.z, sb.w};
    int ed[8] = {da.x, da.y, da.z, da.w, db.x, db.y, db.z, db.w};
    int eb[8];
#pragma unroll
    for (int j = 0; j < 8; ++j) { eb[j] = ed[j] >> 9; atomicAdd(&hist[eb[j]], 1); }
    __syncthreads();
    for (int i = tid; i < NB; i += 256) {
        int c = hist[i];
        cur[i] = (c > 0) ? atomicAdd(&bucket_cnt[i], c) : 0;
    }
    __syncthreads();
#pragma unroll
    for (int j = 0; j < 8; ++j) {
        int p = atomicAdd(&cur[eb[j]], 1);
        if (p < BCAP) arena[(size_t)eb[j] * BCAP + p] = make_int2(es[j], ed[j] & 511);
    }
}

// Exclusive scan of 196 bucket counts.
__global__ __launch_bounds__(256) void k_bscan(const int* __restrict__ bucket_cnt, int* __restrict__ bucket_base) {
    __shared__ int s[256];
    int t = threadIdx.x;
    int v = (t < NB) ? bucket_cnt[t] : 0;
    s[t] = v;
    __syncthreads();
    for (int o = 1; o < 256; o <<= 1) {
        int a = (t >= o) ? s[t - o] : 0;
        __syncthreads();
        s[t] += a;
        __syncthreads();
    }
    if (t < NB) bucket_base[t] = s[t] - v;
}

// Pass 2: per bucket (512 nodes): deg + row_ptr + dis via LDS, CSR via LDS staging,
// all global writes coalesced.
__global__ __launch_bounds__(256) void k_build(const int2* __restrict__ arena, const int* __restrict__ bucket_cnt,
                                               const int* __restrict__ bucket_base, int* __restrict__ row_ptr,
                                               int* __restrict__ deg, float* __restrict__ dis,
                                               int* __restrict__ csr_src) {
    __shared__ int dloc[512];
    __shared__ int sc[512];
    __shared__ int cur[512];
    __shared__ int stage[LCAP];
    int b = blockIdx.x;
    int tid = threadIdx.x;
    int nb = min(bucket_cnt[b], BCAP);
    int gbase = bucket_base[b];
    const int2* ap = arena + (size_t)b * BCAP;
    for (int i = tid; i < 512; i += 256) dloc[i] = 0;
    __syncthreads();
    for (int i = tid; i < nb; i += 256) {
        int2 e = ap[i];
        atomicAdd(&dloc[e.y], 1);
    }
    __syncthreads();
    for (int i = tid; i < 512; i += 256) sc[i] = dloc[i];
    __syncthreads();
    for (int o = 1; o < 512; o <<= 1) {        // Hillis-Steele inclusive scan, 512 elems
        int i0 = tid, i1 = tid + 256;
        int v0 = (i0 >= o) ? sc[i0 - o] : 0;
        int v1 = (i1 >= o) ? sc[i1 - o] : 0;
        __syncthreads();
        sc[i0] += v0;
        sc[i1] += v1;
        __syncthreads();
    }
    for (int i = tid; i < 512; i += 256) {
        int d = dloc[i];
        int off = sc[i] - d;                   // exclusive prefix
        int node = b * 512 + i;
        row_ptr[node] = gbase + off;
        deg[node] = d;
        dis[node] = (float)(1.0 / sqrt((double)(d + 1)));   // +1 self-loop
        cur[i] = off;
    }
    __syncthreads();
    bool inlds = (nb <= LCAP);
    for (int i = tid; i < nb; i += 256) {
        int2 e = ap[i];
        int p = atomicAdd(&cur[e.y], 1);
        if (inlds) stage[p] = e.x;
        else       csr_src[gbase + p] = e.x;   // statistically unreachable fallback
    }
    __syncthreads();
    if (inlds)
        for (int i = tid; i < nb; i += 256) csr_src[gbase + i] = stage[i];
}

// xw1s = dis[n] * (x @ W1). W1 in LDS; lane = col; 8 nodes in flight per thread.
#define MM1_NPW 8
__global__ __launch_bounds__(256) void k_mm1(const float* __restrict__ x, const float* __restrict__ W1,
                                             const float* __restrict__ dis, float* __restrict__ xw1s) {
    __shared__ float wlds[IN_C * HID_C];   // 32 KB
    int tid = threadIdx.x;
    for (int i = tid; i < IN_C * HID_C / 4; i += 256)
        ((float4*)wlds)[i] = ((const float4*)W1)[i];
    __syncthreads();
    int lane = tid & 63;
    int wid = blockIdx.x * 4 + (tid >> 6);
    int n0 = wid * MM1_NPW;
    const float* xb = x + (size_t)n0 * IN_C;
    float acc[MM1_NPW] = {0.f, 0.f, 0.f, 0.f, 0.f, 0.f, 0.f, 0.f};
#pragma unroll 4
    for (int q = 0; q < IN_C / 4; ++q) {
        float4 xv[MM1_NPW];
#pragma unroll
        for (int j = 0; j < MM1_NPW; ++j)
            xv[j] = *(const float4*)(xb + j * IN_C + 4 * q);   // wave-uniform -> broadcast
#pragma unroll
        for (int kk = 0; kk < 4; ++kk) {
            float wv = wlds[(4 * q + kk) * HID_C + lane];
#pragma unroll
            for (int j = 0; j < MM1_NPW; ++j) {
                float xs = (kk == 0) ? xv[j].x : (kk == 1) ? xv[j].y : (kk == 2) ? xv[j].z : xv[j].w;
                acc[j] = fmaf(xs, wv, acc[j]);
            }
        }
    }
#pragma unroll
    for (int j = 0; j < MM1_NPW; ++j)
        xw1s[(size_t)(n0 + j) * HID_C + lane] = acc[j] * dis[n0 + j];
}

// layer-1 aggregation: one 64-lane wave per node; dis folded; 8 gather loads in flight.
__global__ __launch_bounds__(256) void k_agg1(const float* __restrict__ xw1s, const int* __restrict__ csr_src,
                                              const int* __restrict__ row_ptr, const int* __restrict__ deg,
                                              const float* __restrict__ dis, const float* __restrict__ b1,
                                              float* __restrict__ h) {
    int lane = threadIdx.x & 63;
    int v = blockIdx.x * 4 + (threadIdx.x >> 6);
    int start = row_ptr[v];
    int cnt = deg[v];
    float acc0 = xw1s[(size_t)v * HID_C + lane];   // self-loop term (already dis-scaled)
    float acc1 = 0.f, acc2 = 0.f, acc3 = 0.f;
    for (int base = 0; base < cnt; base += 64) {
        int mcnt = min(64, cnt - base);
        int sj = 0;
        if (lane < mcnt) sj = csr_src[start + base + lane];
        int j = 0;
        for (; j + 8 <= mcnt; j += 8) {
            int s0 = __shfl(sj, j + 0), s1 = __shfl(sj, j + 1);
            int s2 = __shfl(sj, j + 2), s3 = __shfl(sj, j + 3);
            int s4 = __shfl(sj, j + 4), s5 = __shfl(sj, j + 5);
            int s6 = __shfl(sj, j + 6), s7 = __shfl(sj, j + 7);
            float v0 = xw1s[(size_t)s0 * HID_C + lane];
            float v1 = xw1s[(size_t)s1 * HID_C + lane];
            float v2 = xw1s[(size_t)s2 * HID_C + lane];
            float v3 = xw1s[(size_t)s3 * HID_C + lane];
            float v4 = xw1s[(size_t)s4 * HID_C + lane];
            float v5 = xw1s[(size_t)s5 * HID_C + lane];
            float v6 = xw1s[(size_t)s6 * HID_C + lane];
            float v7 = xw1s[(size_t)s7 * HID_C + lane];
            acc0 += v0 + v4;
            acc1 += v1 + v5;
            acc2 += v2 + v6;
            acc3 += v3 + v7;
        }
        for (; j < mcnt; ++j) {
            int s = __shfl(sj, j);
            acc0 += xw1s[(size_t)s * HID_C + lane];
        }
    }
    float o = fmaf(dis[v], (acc0 + acc1) + (acc2 + acc3), b1[lane]);
    h[(size_t)v * HID_C + lane] = fmaxf(o, 0.f);   // ReLU fused
}

// xw2s = dis[n] * (h @ W2). W2 in LDS; half-wave = node slot; 8 nodes per half-wave.
#define MM2_NPW 8
__global__ __launch_bounds__(256) void k_mm2(const float* __restrict__ h, const float* __restrict__ W2,
                                             const float* __restrict__ dis, float* __restrict__ xw2s) {
    __shared__ float wlds[HID_C * OUT_C];   // 8 KB
    int tid = threadIdx.x;
    for (int i = tid; i < HID_C * OUT_C / 4; i += 256)
        ((float4*)wlds)[i] = ((const float4*)W2)[i];
    __syncthreads();
    int lane = tid & 63;
    int c = lane & 31;
    int half = lane >> 5;
    int wid = blockIdx.x * 4 + (tid >> 6);
    int n0 = wid * 2 * MM2_NPW;             // 16 nodes per wave
    const float* hb = h + (size_t)(n0 + half) * HID_C;
    float acc[MM2_NPW] = {0.f, 0.f, 0.f, 0.f, 0.f, 0.f, 0.f, 0.f};
#pragma unroll 4
    for (int q = 0; q < HID_C / 4; ++q) {
        float4 xv[MM2_NPW];
#pragma unroll
        for (int j = 0; j < MM2_NPW; ++j)
            xv[j] = *(const float4*)(hb + (size_t)(2 * j) * HID_C + 4 * q);
#pragma unroll
        for (int kk = 0; kk < 4; ++kk) {
            float wv = wlds[(4 * q + kk) * OUT_C + c];
#pragma unroll
            for (int j = 0; j < MM2_NPW; ++j) {
                float xs = (kk == 0) ? xv[j].x : (kk == 1) ? xv[j].y : (kk == 2) ? xv[j].z : xv[j].w;
                acc[j] = fmaf(xs, wv, acc[j]);
            }
        }
    }
#pragma unroll
    for (int j = 0; j < MM2_NPW; ++j) {
        int n = n0 + 2 * j + half;
        xw2s[(size_t)n * OUT_C + c] = acc[j] * dis[n];
    }
}

// layer-2 aggregation: 32-lane group per node; dis folded; 8 gather loads in flight.
__global__ __launch_bounds__(256) void k_agg2(const float* __restrict__ xw2s, const int* __restrict__ csr_src,
                                              const int* __restrict__ row_ptr, const int* __restrict__ deg,
                                              const float* __restrict__ dis, const float* __restrict__ b2,
                                              float* __restrict__ out2) {
    int lane = threadIdx.x & 31;
    int v = blockIdx.x * 8 + (threadIdx.x >> 5);
    int start = row_ptr[v];
    int cnt = deg[v];
    float acc0 = xw2s[(size_t)v * OUT_C + lane];   // self-loop term
    float acc1 = 0.f, acc2 = 0.f, acc3 = 0.f;
    for (int base = 0; base < cnt; base += 32) {
        int mcnt = min(32, cnt - base);
        int sj = 0;
        if (lane < mcnt) sj = csr_src[start + base + lane];
        int j = 0;
        for (; j + 8 <= mcnt; j += 8) {
            int s0 = __shfl(sj, j + 0, 32), s1 = __shfl(sj, j + 1, 32);
            int s2 = __shfl(sj, j + 2, 32), s3 = __shfl(sj, j + 3, 32);
            int s4 = __shfl(sj, j + 4, 32), s5 = __shfl(sj, j + 5, 32);
            int s6 = __shfl(sj, j + 6, 32), s7 = __shfl(sj, j + 7, 32);
            float v0 = xw2s[(size_t)s0 * OUT_C + lane];
            float v1 = xw2s[(size_t)s1 * OUT_C + lane];
            float v2 = xw2s[(size_t)s2 * OUT_C + lane];
            float v3 = xw2s[(size_t)s3 * OUT_C + lane];
            float v4 = xw2s[(size_t)s4 * OUT_C + lane];
            float v5 = xw2s[(size_t)s5 * OUT_C + lane];
            float v6 = xw2s[(size_t)s6 * OUT_C + lane];
            float v7 = xw2s[(size_t)s7 * OUT_C + lane];
            acc0 += v0 + v4;
            acc1 += v1 + v5;
            acc2 += v2 + v6;
            acc3 += v3 + v7;
        }
        for (; j < mcnt; ++j) {
            int s = __shfl(sj, j, 32);
            acc0 += xw2s[(size_t)s * OUT_C + lane];
        }
    }
    out2[(size_t)v * OUT_C + lane] = fmaf(dis[v], (acc0 + acc1) + (acc2 + acc3), b2[lane]);
}

// per-graph top-30 by channel 31 (desc, stable), emit [512, 30*32] f32.
__global__ __launch_bounds__(256) void k_sort(const float* __restrict__ out2, float* __restrict__ out) {
    __shared__ float keys[NPG];
    __shared__ int order[TOPK];
    int g = blockIdx.x;
    int tid = threadIdx.x;
    int base = g * NPG;
    if (tid < NPG) keys[tid] = out2[(size_t)(base + tid) * OUT_C + (OUT_C - 1)];
    __syncthreads();
    if (tid < NPG) {
        float my = keys[tid];
        int r = 0;
        for (int j = 0; j < NPG; ++j) {
            float kj = keys[j];
            r += (kj > my) || (kj == my && j < tid);
        }
        if (r < TOPK) order[r] = tid;
    }
    __syncthreads();
    for (int idx = tid; idx < TOPK * OUT_C; idx += 256) {
        int r = idx >> 5;
        int c = idx & 31;
        int n = order[r];
        out[g * (TOPK * OUT_C) + idx] = out2[(size_t)(base + n) * OUT_C + c];
    }
}

extern "C" void kernel_launch(void* const* d_in, const int* in_sizes, int n_in,
                              void* d_out, int out_size, void* d_ws, size_t ws_size,
                              hipStream_t stream) {
    const float* x  = (const float*)d_in[0];
    const int*   ei = (const int*)d_in[1];
    const int*   srcp = ei;             // edge_index[0]
    const int*   dstp = ei + N_EDGES;   // edge_index[1]
    // d_in[2] (batch) unused: graphs are contiguous 196-node blocks.
    const float* W1 = (const float*)d_in[3];
    const float* b1 = (const float*)d_in[4];
    const float* W2 = (const float*)d_in[5];
    const float* b2 = (const float*)d_in[6];
    float* out = (float*)d_out;

    char* w = (char*)d_ws;
    int*    deg      = (int*)(w + OFF_DEG);
    int*    row_ptr  = (int*)(w + OFF_ROWPTR);
    float*  dis      = (float*)(w + OFF_DIS);
    int*    bcnt     = (int*)(w + OFF_BCNT);
    int*    bbase    = (int*)(w + OFF_BBASE);
    int2*   arena    = (int2*)(w + OFF_ARENA);
    int*    csr_src  = (int*)(w + OFF_CSR);
    float*  xw1s     = (float*)(w + OFF_XW1);
    float*  h        = (float*)(w + OFF_H);
    float*  xw2s     = (float*)(w + OFF_XW2);
    float*  out2     = (float*)(w + OFF_OUT2);   // aliases arena (dead after k_build)

    hipMemsetAsync(bcnt, 0, NB * sizeof(int), stream);
    k_bucket<<<N_EDGES / (256 * 8), 256, 0, stream>>>(srcp, dstp, bcnt, arena);
    k_bscan <<<1, 256, 0, stream>>>(bcnt, bbase);
    k_build <<<NB, 256, 0, stream>>>(arena, bcnt, bbase, row_ptr, deg, dis, csr_src);
    k_mm1   <<<N_NODES / (MM1_NPW * 4), 256, 0, stream>>>(x, W1, dis, xw1s);
    k_agg1  <<<N_NODES / 4, 256, 0, stream>>>(xw1s, csr_src, row_ptr, deg, dis, b1, h);
    k_mm2   <<<N_NODES / (MM2_NPW * 2 * 4), 256, 0, stream>>>(h, W2, dis, xw2s);
    k_agg2  <<<N_NODES / 8, 256, 0, stream>>>(xw2s, csr_src, row_ptr, deg, dis, b2, out2);
    k_sort  <<<NUM_GRAPHS, 256, 0, stream>>>(out2, out);
}

// Round 7
// 263.476 us; speedup vs baseline: 1.7528x; 1.1203x over previous
//
#include <hip/hip_runtime.h>

#define N_NODES   100352
#define N_EDGES   1605632
#define IN_C      128
#define HID_C     64
#define OUT_C     32
#define NUM_GRAPHS 512
#define NPG       196
#define TOPK      30

#define NB        196     // buckets = dst>>9 (512 nodes each; 196*512 = 100352)
#define BCAP      10240   // arena capacity per bucket (E[nb]=8192, sigma~90)
#define LCAP      10240   // LDS staging capacity in k_build (40 KB)

typedef float v4f __attribute__((ext_vector_type(4)));

// ws layout (bytes)
#define OFF_DEG     0u          // int[N]
#define OFF_ROWPTR  401408u     // int[N]
#define OFF_DIS     802816u     // float[N]
#define OFF_BCNT    1204224u    // int[NB]
#define OFF_BBASE   1205248u    // int[NB]
#define OFF_ARENA   1206272u    // int2[NB*BCAP] = 16,056,320 B  (dead after k_build)
#define OFF_OUT2    1206272u    // float[N*32] = 12,845,056 B  -- aliases arena
#define OFF_CSR     17262592u   // int[E]
#define OFF_XW1     23685120u   // float[N*64]  (dis-scaled)
#define OFF_H       49375232u   // float[N*64]
#define OFF_XW2     75065344u   // float[N*32]  (dis-scaled)

// Pass 1: bucketize edges. LDS histogram -> one global atomic per (block,bucket)
// -> writes to 196 sequential arena windows (sectors fill -> no write amplification).
__global__ __launch_bounds__(256) void k_bucket(const int* __restrict__ src, const int* __restrict__ dst,
                                                int* __restrict__ bucket_cnt, int2* __restrict__ arena) {
    __shared__ int hist[NB];
    __shared__ int cur[NB];
    int tid = threadIdx.x;
    for (int i = tid; i < NB; i += 256) hist[i] = 0;
    __syncthreads();
    int e0 = (blockIdx.x * 256 + tid) * 8;       // 8 edges per thread
    int4 sa = ((const int4*)src)[e0 / 4], sb = ((const int4*)src)[e0 / 4 + 1];
    int4 da = ((const int4*)dst)[e0 / 4], db = ((const int4*)dst)[e0 / 4 + 1];
    int es[8] = {sa.x, sa.y, sa.z, sa.w, sb.x, sb.y, sb.z, sb.w};
    int ed[8] = {da.x, da.y, da.z, da.w, db.x, db.y, db.z, db.w};
    int eb[8];
#pragma unroll
    for (int j = 0; j < 8; ++j) { eb[j] = ed[j] >> 9; atomicAdd(&hist[eb[j]], 1); }
    __syncthreads();
    for (int i = tid; i < NB; i += 256) {
        int c = hist[i];
        cur[i] = (c > 0) ? atomicAdd(&bucket_cnt[i], c) : 0;
    }
    __syncthreads();
#pragma unroll
    for (int j = 0; j < 8; ++j) {
        int p = atomicAdd(&cur[eb[j]], 1);
        if (p < BCAP) arena[(size_t)eb[j] * BCAP + p] = make_int2(es[j], ed[j] & 511);
    }
}

// Exclusive scan of 196 bucket counts.
__global__ __launch_bounds__(256) void k_bscan(const int* __restrict__ bucket_cnt, int* __restrict__ bucket_base) {
    __shared__ int s[256];
    int t = threadIdx.x;
    int v = (t < NB) ? bucket_cnt[t] : 0;
    s[t] = v;
    __syncthreads();
    for (int o = 1; o < 256; o <<= 1) {
        int a = (t >= o) ? s[t - o] : 0;
        __syncthreads();
        s[t] += a;
        __syncthreads();
    }
    if (t < NB) bucket_base[t] = s[t] - v;
}

// Pass 2: per bucket (512 nodes): deg + row_ptr + dis via LDS, CSR via LDS staging.
__global__ __launch_bounds__(256) void k_build(const int2* __restrict__ arena, const int* __restrict__ bucket_cnt,
                                               const int* __restrict__ bucket_base, int* __restrict__ row_ptr,
                                               int* __restrict__ deg, float* __restrict__ dis,
                                               int* __restrict__ csr_src) {
    __shared__ int dloc[512];
    __shared__ int sc[512];
    __shared__ int cur[512];
    __shared__ int stage[LCAP];
    int b = blockIdx.x;
    int tid = threadIdx.x;
    int nb = min(bucket_cnt[b], BCAP);
    int gbase = bucket_base[b];
    const int2* ap = arena + (size_t)b * BCAP;
    for (int i = tid; i < 512; i += 256) dloc[i] = 0;
    __syncthreads();
    for (int i = tid; i < nb; i += 256) {
        int2 e = ap[i];
        atomicAdd(&dloc[e.y], 1);
    }
    __syncthreads();
    for (int i = tid; i < 512; i += 256) sc[i] = dloc[i];
    __syncthreads();
    for (int o = 1; o < 512; o <<= 1) {        // Hillis-Steele inclusive scan, 512 elems
        int i0 = tid, i1 = tid + 256;
        int v0 = (i0 >= o) ? sc[i0 - o] : 0;
        int v1 = (i1 >= o) ? sc[i1 - o] : 0;
        __syncthreads();
        sc[i0] += v0;
        sc[i1] += v1;
        __syncthreads();
    }
    for (int i = tid; i < 512; i += 256) {
        int d = dloc[i];
        int off = sc[i] - d;                   // exclusive prefix
        int node = b * 512 + i;
        row_ptr[node] = gbase + off;
        deg[node] = d;
        dis[node] = (float)(1.0 / sqrt((double)(d + 1)));   // +1 self-loop
        cur[i] = off;
    }
    __syncthreads();
    bool inlds = (nb <= LCAP);
    for (int i = tid; i < nb; i += 256) {
        int2 e = ap[i];
        int p = atomicAdd(&cur[e.y], 1);
        if (inlds) stage[p] = e.x;
        else       csr_src[gbase + p] = e.x;
    }
    __syncthreads();
    if (inlds)
        for (int i = tid; i < nb; i += 256) csr_src[gbase + i] = stage[i];
}

// xw1s = dis[n] * (x @ W1). W1 in LDS; lane = col; 8 nodes per wave.
// x rows are wave-uniform -> loaded on the SCALAR pipe (s_load_dwordx4).
// FMAs consume SGPR x + VGPR w (1 SGPR source per VALU instr: legal).
__global__ __launch_bounds__(256) void k_mm1(const float* __restrict__ x, const float* __restrict__ W1,
                                             const float* __restrict__ dis, float* __restrict__ xw1s) {
    __shared__ float wlds[IN_C * HID_C];   // 32 KB [k][c]
    int tid = threadIdx.x;
    for (int i = tid; i < IN_C * HID_C / 4; i += 256)
        ((float4*)wlds)[i] = ((const float4*)W1)[i];
    __syncthreads();
    int lane = tid & 63;
    int wid = blockIdx.x * 4 + (tid >> 6);
    int n0 = __builtin_amdgcn_readfirstlane(wid * 8);   // scalarize -> address math stays on SALU
    const float* xb = x + (size_t)n0 * IN_C;
    float acc0 = 0.f, acc1 = 0.f, acc2 = 0.f, acc3 = 0.f;
    float acc4 = 0.f, acc5 = 0.f, acc6 = 0.f, acc7 = 0.f;
#pragma unroll 2
    for (int q = 0; q < IN_C / 4; ++q) {
        const float* xq = xb + 4 * q;          // scalar; node j at byte offset j*512
        v4f s0, s1, s2, s3, s4, s5, s6, s7;
        asm volatile("s_load_dwordx4 %0, %1, 0x0"   : "=s"(s0) : "s"(xq));
        asm volatile("s_load_dwordx4 %0, %1, 0x200" : "=s"(s1) : "s"(xq));
        asm volatile("s_load_dwordx4 %0, %1, 0x400" : "=s"(s2) : "s"(xq));
        asm volatile("s_load_dwordx4 %0, %1, 0x600" : "=s"(s3) : "s"(xq));
        asm volatile("s_load_dwordx4 %0, %1, 0x800" : "=s"(s4) : "s"(xq));
        asm volatile("s_load_dwordx4 %0, %1, 0xa00" : "=s"(s5) : "s"(xq));
        asm volatile("s_load_dwordx4 %0, %1, 0xc00" : "=s"(s6) : "s"(xq));
        asm volatile("s_load_dwordx4 %0, %1, 0xe00" : "=s"(s7) : "s"(xq));
        // tie the wait to the loaded values so consumers can't be scheduled above it
        asm volatile("s_waitcnt lgkmcnt(0)"
                     : "+s"(s0), "+s"(s1), "+s"(s2), "+s"(s3),
                       "+s"(s4), "+s"(s5), "+s"(s6), "+s"(s7));
#pragma unroll
        for (int kk = 0; kk < 4; ++kk) {
            float wv = wlds[(4 * q + kk) * HID_C + lane];
            acc0 = fmaf(s0[kk], wv, acc0);
            acc1 = fmaf(s1[kk], wv, acc1);
            acc2 = fmaf(s2[kk], wv, acc2);
            acc3 = fmaf(s3[kk], wv, acc3);
            acc4 = fmaf(s4[kk], wv, acc4);
            acc5 = fmaf(s5[kk], wv, acc5);
            acc6 = fmaf(s6[kk], wv, acc6);
            acc7 = fmaf(s7[kk], wv, acc7);
        }
    }
    xw1s[(size_t)(n0 + 0) * HID_C + lane] = acc0 * dis[n0 + 0];
    xw1s[(size_t)(n0 + 1) * HID_C + lane] = acc1 * dis[n0 + 1];
    xw1s[(size_t)(n0 + 2) * HID_C + lane] = acc2 * dis[n0 + 2];
    xw1s[(size_t)(n0 + 3) * HID_C + lane] = acc3 * dis[n0 + 3];
    xw1s[(size_t)(n0 + 4) * HID_C + lane] = acc4 * dis[n0 + 4];
    xw1s[(size_t)(n0 + 5) * HID_C + lane] = acc5 * dis[n0 + 5];
    xw1s[(size_t)(n0 + 6) * HID_C + lane] = acc6 * dis[n0 + 6];
    xw1s[(size_t)(n0 + 7) * HID_C + lane] = acc7 * dis[n0 + 7];
}

// layer-1 aggregation: one 64-lane wave per node; dis folded; 8 gather loads in flight.
__global__ __launch_bounds__(256) void k_agg1(const float* __restrict__ xw1s, const int* __restrict__ csr_src,
                                              const int* __restrict__ row_ptr, const int* __restrict__ deg,
                                              const float* __restrict__ dis, const float* __restrict__ b1,
                                              float* __restrict__ h) {
    int lane = threadIdx.x & 63;
    int v = blockIdx.x * 4 + (threadIdx.x >> 6);
    int start = row_ptr[v];
    int cnt = deg[v];
    float acc0 = xw1s[(size_t)v * HID_C + lane];   // self-loop term (already dis-scaled)
    float acc1 = 0.f, acc2 = 0.f, acc3 = 0.f;
    for (int base = 0; base < cnt; base += 64) {
        int mcnt = min(64, cnt - base);
        int sj = 0;
        if (lane < mcnt) sj = csr_src[start + base + lane];
        int j = 0;
        for (; j + 8 <= mcnt; j += 8) {
            int s0 = __shfl(sj, j + 0), s1 = __shfl(sj, j + 1);
            int s2 = __shfl(sj, j + 2), s3 = __shfl(sj, j + 3);
            int s4 = __shfl(sj, j + 4), s5 = __shfl(sj, j + 5);
            int s6 = __shfl(sj, j + 6), s7 = __shfl(sj, j + 7);
            float v0 = xw1s[(size_t)s0 * HID_C + lane];
            float v1 = xw1s[(size_t)s1 * HID_C + lane];
            float v2 = xw1s[(size_t)s2 * HID_C + lane];
            float v3 = xw1s[(size_t)s3 * HID_C + lane];
            float v4 = xw1s[(size_t)s4 * HID_C + lane];
            float v5 = xw1s[(size_t)s5 * HID_C + lane];
            float v6 = xw1s[(size_t)s6 * HID_C + lane];
            float v7 = xw1s[(size_t)s7 * HID_C + lane];
            acc0 += v0 + v4;
            acc1 += v1 + v5;
            acc2 += v2 + v6;
            acc3 += v3 + v7;
        }
        for (; j < mcnt; ++j) {
            int s = __shfl(sj, j);
            acc0 += xw1s[(size_t)s * HID_C + lane];
        }
    }
    float o = fmaf(dis[v], (acc0 + acc1) + (acc2 + acc3), b1[lane]);
    h[(size_t)v * HID_C + lane] = fmaxf(o, 0.f);   // ReLU fused
}

// xw2s = dis[n] * (h @ W2). W2 (8 KB) in LDS. 16 nodes per wave via scalar x loads:
// all lanes compute FMA streams for two node-sets; lanes 0-31 store set A, 32-63 set B.
__global__ __launch_bounds__(256) void k_mm2(const float* __restrict__ h, const float* __restrict__ W2,
                                             const float* __restrict__ dis, float* __restrict__ xw2s) {
    __shared__ float wlds[HID_C * OUT_C];   // 8 KB [k][c]
    int tid = threadIdx.x;
    for (int i = tid; i < HID_C * OUT_C / 4; i += 256)
        ((float4*)wlds)[i] = ((const float4*)W2)[i];
    __syncthreads();
    int lane = tid & 63;
    int c = lane & 31;
    int half = lane >> 5;
    int wid = blockIdx.x * 4 + (tid >> 6);
    int n0 = __builtin_amdgcn_readfirstlane(wid * 16);
    const float* hb = h + (size_t)n0 * HID_C;
    float accA[8] = {0.f, 0.f, 0.f, 0.f, 0.f, 0.f, 0.f, 0.f};
    float accB[8] = {0.f, 0.f, 0.f, 0.f, 0.f, 0.f, 0.f, 0.f};
#pragma unroll 2
    for (int q = 0; q < HID_C / 4; ++q) {
        const float* hq = hb + 4 * q;          // node j at byte offset j*256
        v4f a0, a1, a2, a3, a4, a5, a6, a7;
        v4f b0, b1v, b2, b3, b4, b5, b6, b7;
        asm volatile("s_load_dwordx4 %0, %1, 0x0"   : "=s"(a0)  : "s"(hq));
        asm volatile("s_load_dwordx4 %0, %1, 0x100" : "=s"(a1)  : "s"(hq));
        asm volatile("s_load_dwordx4 %0, %1, 0x200" : "=s"(a2)  : "s"(hq));
        asm volatile("s_load_dwordx4 %0, %1, 0x300" : "=s"(a3)  : "s"(hq));
        asm volatile("s_load_dwordx4 %0, %1, 0x400" : "=s"(a4)  : "s"(hq));
        asm volatile("s_load_dwordx4 %0, %1, 0x500" : "=s"(a5)  : "s"(hq));
        asm volatile("s_load_dwordx4 %0, %1, 0x600" : "=s"(a6)  : "s"(hq));
        asm volatile("s_load_dwordx4 %0, %1, 0x700" : "=s"(a7)  : "s"(hq));
        asm volatile("s_load_dwordx4 %0, %1, 0x800" : "=s"(b0)  : "s"(hq));
        asm volatile("s_load_dwordx4 %0, %1, 0x900" : "=s"(b1v) : "s"(hq));
        asm volatile("s_load_dwordx4 %0, %1, 0xa00" : "=s"(b2)  : "s"(hq));
        asm volatile("s_load_dwordx4 %0, %1, 0xb00" : "=s"(b3)  : "s"(hq));
        asm volatile("s_load_dwordx4 %0, %1, 0xc00" : "=s"(b4)  : "s"(hq));
        asm volatile("s_load_dwordx4 %0, %1, 0xd00" : "=s"(b5)  : "s"(hq));
        asm volatile("s_load_dwordx4 %0, %1, 0xe00" : "=s"(b6)  : "s"(hq));
        asm volatile("s_load_dwordx4 %0, %1, 0xf00" : "=s"(b7)  : "s"(hq));
        asm volatile("s_waitcnt lgkmcnt(0)"
                     : "+s"(a0), "+s"(a1), "+s"(a2), "+s"(a3),
                       "+s"(a4), "+s"(a5), "+s"(a6), "+s"(a7),
                       "+s"(b0), "+s"(b1v), "+s"(b2), "+s"(b3),
                       "+s"(b4), "+s"(b5), "+s"(b6), "+s"(b7));
#pragma unroll
        for (int kk = 0; kk < 4; ++kk) {
            float wv = wlds[(4 * q + kk) * OUT_C + c];
            accA[0] = fmaf(a0[kk],  wv, accA[0]);
            accA[1] = fmaf(a1[kk],  wv, accA[1]);
            accA[2] = fmaf(a2[kk],  wv, accA[2]);
            accA[3] = fmaf(a3[kk],  wv, accA[3]);
            accA[4] = fmaf(a4[kk],  wv, accA[4]);
            accA[5] = fmaf(a5[kk],  wv, accA[5]);
            accA[6] = fmaf(a6[kk],  wv, accA[6]);
            accA[7] = fmaf(a7[kk],  wv, accA[7]);
            accB[0] = fmaf(b0[kk],  wv, accB[0]);
            accB[1] = fmaf(b1v[kk], wv, accB[1]);
            accB[2] = fmaf(b2[kk],  wv, accB[2]);
            accB[3] = fmaf(b3[kk],  wv, accB[3]);
            accB[4] = fmaf(b4[kk],  wv, accB[4]);
            accB[5] = fmaf(b5[kk],  wv, accB[5]);
            accB[6] = fmaf(b6[kk],  wv, accB[6]);
            accB[7] = fmaf(b7[kk],  wv, accB[7]);
        }
    }
#pragma unroll
    for (int j = 0; j < 8; ++j) {
        int n = n0 + j + half * 8;
        float vst = half ? accB[j] : accA[j];
        xw2s[(size_t)n * OUT_C + c] = vst * dis[n];
    }
}

// layer-2 aggregation: 32-lane group per node; dis folded; 8 gather loads in flight.
__global__ __launch_bounds__(256) void k_agg2(const float* __restrict__ xw2s, const int* __restrict__ csr_src,
                                              const int* __restrict__ row_ptr, const int* __restrict__ deg,
                                              const float* __restrict__ dis, const float* __restrict__ b2,
                                              float* __restrict__ out2) {
    int lane = threadIdx.x & 31;
    int v = blockIdx.x * 8 + (threadIdx.x >> 5);
    int start = row_ptr[v];
    int cnt = deg[v];
    float acc0 = xw2s[(size_t)v * OUT_C + lane];   // self-loop term
    float acc1 = 0.f, acc2 = 0.f, acc3 = 0.f;
    for (int base = 0; base < cnt; base += 32) {
        int mcnt = min(32, cnt - base);
        int sj = 0;
        if (lane < mcnt) sj = csr_src[start + base + lane];
        int j = 0;
        for (; j + 8 <= mcnt; j += 8) {
            int s0 = __shfl(sj, j + 0, 32), s1 = __shfl(sj, j + 1, 32);
            int s2 = __shfl(sj, j + 2, 32), s3 = __shfl(sj, j + 3, 32);
            int s4 = __shfl(sj, j + 4, 32), s5 = __shfl(sj, j + 5, 32);
            int s6 = __shfl(sj, j + 6, 32), s7 = __shfl(sj, j + 7, 32);
            float v0 = xw2s[(size_t)s0 * OUT_C + lane];
            float v1 = xw2s[(size_t)s1 * OUT_C + lane];
            float v2 = xw2s[(size_t)s2 * OUT_C + lane];
            float v3 = xw2s[(size_t)s3 * OUT_C + lane];
            float v4 = xw2s[(size_t)s4 * OUT_C + lane];
            float v5 = xw2s[(size_t)s5 * OUT_C + lane];
            float v6 = xw2s[(size_t)s6 * OUT_C + lane];
            float v7 = xw2s[(size_t)s7 * OUT_C + lane];
            acc0 += v0 + v4;
            acc1 += v1 + v5;
            acc2 += v2 + v6;
            acc3 += v3 + v7;
        }
        for (; j < mcnt; ++j) {
            int s = __shfl(sj, j, 32);
            acc0 += xw2s[(size_t)s * OUT_C + lane];
        }
    }
    out2[(size_t)v * OUT_C + lane] = fmaf(dis[v], (acc0 + acc1) + (acc2 + acc3), b2[lane]);
}

// per-graph top-30 by channel 31 (desc, stable), emit [512, 30*32] f32.
__global__ __launch_bounds__(256) void k_sort(const float* __restrict__ out2, float* __restrict__ out) {
    __shared__ float keys[NPG];
    __shared__ int order[TOPK];
    int g = blockIdx.x;
    int tid = threadIdx.x;
    int base = g * NPG;
    if (tid < NPG) keys[tid] = out2[(size_t)(base + tid) * OUT_C + (OUT_C - 1)];
    __syncthreads();
    if (tid < NPG) {
        float my = keys[tid];
        int r = 0;
        for (int j = 0; j < NPG; ++j) {
            float kj = keys[j];
            r += (kj > my) || (kj == my && j < tid);
        }
        if (r < TOPK) order[r] = tid;
    }
    __syncthreads();
    for (int idx = tid; idx < TOPK * OUT_C; idx += 256) {
        int r = idx >> 5;
        int c = idx & 31;
        int n = order[r];
        out[g * (TOPK * OUT_C) + idx] = out2[(size_t)(base + n) * OUT_C + c];
    }
}

extern "C" void kernel_launch(void* const* d_in, const int* in_sizes, int n_in,
                              void* d_out, int out_size, void* d_ws, size_t ws_size,
                              hipStream_t stream) {
    const float* x  = (const float*)d_in[0];
    const int*   ei = (const int*)d_in[1];
    const int*   srcp = ei;             // edge_index[0]
    const int*   dstp = ei + N_EDGES;   // edge_index[1]
    // d_in[2] (batch) unused: graphs are contiguous 196-node blocks.
    const float* W1 = (const float*)d_in[3];
    const float* b1 = (const float*)d_in[4];
    const float* W2 = (const float*)d_in[5];
    const float* b2 = (const float*)d_in[6];
    float* out = (float*)d_out;

    char* w = (char*)d_ws;
    int*    deg      = (int*)(w + OFF_DEG);
    int*    row_ptr  = (int*)(w + OFF_ROWPTR);
    float*  dis      = (float*)(w + OFF_DIS);
    int*    bcnt     = (int*)(w + OFF_BCNT);
    int*    bbase    = (int*)(w + OFF_BBASE);
    int2*   arena    = (int2*)(w + OFF_ARENA);
    int*    csr_src  = (int*)(w + OFF_CSR);
    float*  xw1s     = (float*)(w + OFF_XW1);
    float*  h        = (float*)(w + OFF_H);
    float*  xw2s     = (float*)(w + OFF_XW2);
    float*  out2     = (float*)(w + OFF_OUT2);   // aliases arena (dead after k_build)

    hipMemsetAsync(bcnt, 0, NB * sizeof(int), stream);
    k_bucket<<<N_EDGES / (256 * 8), 256, 0, stream>>>(srcp, dstp, bcnt, arena);
    k_bscan <<<1, 256, 0, stream>>>(bcnt, bbase);
    k_build <<<NB, 256, 0, stream>>>(arena, bcnt, bbase, row_ptr, deg, dis, csr_src);
    k_mm1   <<<N_NODES / (8 * 4), 256, 0, stream>>>(x, W1, dis, xw1s);
    k_agg1  <<<N_NODES / 4, 256, 0, stream>>>(xw1s, csr_src, row_ptr, deg, dis, b1, h);
    k_mm2   <<<N_NODES / (16 * 4), 256, 0, stream>>>(h, W2, dis, xw2s);
    k_agg2  <<<N_NODES / 8, 256, 0, stream>>>(xw2s, csr_src, row_ptr, deg, dis, b2, out2);
    k_sort  <<<NUM_GRAPHS, 256, 0, stream>>>(out2, out);
}

// Round 8
// 245.048 us; speedup vs baseline: 1.8846x; 1.0752x over previous
//
#include <hip/hip_runtime.h>

#define N_NODES   100352
#define N_EDGES   1605632
#define IN_C      128
#define HID_C     64
#define OUT_C     32
#define NUM_GRAPHS 512
#define NPG       196
#define TOPK      30

#define NB        196     // buckets = dst>>9 (512 nodes each; 196*512 = 100352)
#define BCAP      10240   // arena capacity per bucket (E[nb]=8192, sigma~90)
#define LCAP      10240   // LDS staging capacity in k_build (40 KB)

typedef float v16f __attribute__((ext_vector_type(16)));

// ws layout (bytes)
#define OFF_DEG     0u          // int[N]
#define OFF_ROWPTR  401408u     // int[N]
#define OFF_DIS     802816u     // float[N]
#define OFF_BCNT    1204224u    // int[NB]
#define OFF_BBASE   1205248u    // int[NB]
#define OFF_ARENA   1206272u    // int2[NB*BCAP] = 16,056,320 B  (dead after k_build)
#define OFF_OUT2    1206272u    // float[N*32] = 12,845,056 B  -- aliases arena
#define OFF_CSR     17262592u   // int[E]
#define OFF_XW1     23685120u   // float[N*64]  (dis-scaled)
#define OFF_H       49375232u   // float[N*64]
#define OFF_XW2     75065344u   // float[N*32]  (dis-scaled)

// Pass 1: bucketize edges. LDS histogram -> one global atomic per (block,bucket)
// -> writes to 196 sequential arena windows (sectors fill -> no write amplification).
__global__ __launch_bounds__(256) void k_bucket(const int* __restrict__ src, const int* __restrict__ dst,
                                                int* __restrict__ bucket_cnt, int2* __restrict__ arena) {
    __shared__ int hist[NB];
    __shared__ int cur[NB];
    int tid = threadIdx.x;
    for (int i = tid; i < NB; i += 256) hist[i] = 0;
    __syncthreads();
    int e0 = (blockIdx.x * 256 + tid) * 8;       // 8 edges per thread
    int4 sa = ((const int4*)src)[e0 / 4], sb = ((const int4*)src)[e0 / 4 + 1];
    int4 da = ((const int4*)dst)[e0 / 4], db = ((const int4*)dst)[e0 / 4 + 1];
    int es[8] = {sa.x, sa.y, sa.z, sa.w, sb.x, sb.y, sb.z, sb.w};
    int ed[8] = {da.x, da.y, da.z, da.w, db.x, db.y, db.z, db.w};
    int eb[8];
#pragma unroll
    for (int j = 0; j < 8; ++j) { eb[j] = ed[j] >> 9; atomicAdd(&hist[eb[j]], 1); }
    __syncthreads();
    for (int i = tid; i < NB; i += 256) {
        int c = hist[i];
        cur[i] = (c > 0) ? atomicAdd(&bucket_cnt[i], c) : 0;
    }
    __syncthreads();
#pragma unroll
    for (int j = 0; j < 8; ++j) {
        int p = atomicAdd(&cur[eb[j]], 1);
        if (p < BCAP) arena[(size_t)eb[j] * BCAP + p] = make_int2(es[j], ed[j] & 511);
    }
}

// Exclusive scan of 196 bucket counts.
__global__ __launch_bounds__(256) void k_bscan(const int* __restrict__ bucket_cnt, int* __restrict__ bucket_base) {
    __shared__ int s[256];
    int t = threadIdx.x;
    int v = (t < NB) ? bucket_cnt[t] : 0;
    s[t] = v;
    __syncthreads();
    for (int o = 1; o < 256; o <<= 1) {
        int a = (t >= o) ? s[t - o] : 0;
        __syncthreads();
        s[t] += a;
        __syncthreads();
    }
    if (t < NB) bucket_base[t] = s[t] - v;
}

// Pass 2: per bucket (512 nodes): deg + row_ptr + dis via LDS, CSR via LDS staging.
__global__ __launch_bounds__(256) void k_build(const int2* __restrict__ arena, const int* __restrict__ bucket_cnt,
                                               const int* __restrict__ bucket_base, int* __restrict__ row_ptr,
                                               int* __restrict__ deg, float* __restrict__ dis,
                                               int* __restrict__ csr_src) {
    __shared__ int dloc[512];
    __shared__ int sc[512];
    __shared__ int cur[512];
    __shared__ int stage[LCAP];
    int b = blockIdx.x;
    int tid = threadIdx.x;
    int nb = min(bucket_cnt[b], BCAP);
    int gbase = bucket_base[b];
    const int2* ap = arena + (size_t)b * BCAP;
    for (int i = tid; i < 512; i += 256) dloc[i] = 0;
    __syncthreads();
    for (int i = tid; i < nb; i += 256) {
        int2 e = ap[i];
        atomicAdd(&dloc[e.y], 1);
    }
    __syncthreads();
    for (int i = tid; i < 512; i += 256) sc[i] = dloc[i];
    __syncthreads();
    for (int o = 1; o < 512; o <<= 1) {        // Hillis-Steele inclusive scan, 512 elems
        int i0 = tid, i1 = tid + 256;
        int v0 = (i0 >= o) ? sc[i0 - o] : 0;
        int v1 = (i1 >= o) ? sc[i1 - o] : 0;
        __syncthreads();
        sc[i0] += v0;
        sc[i1] += v1;
        __syncthreads();
    }
    for (int i = tid; i < 512; i += 256) {
        int d = dloc[i];
        int off = sc[i] - d;                   // exclusive prefix
        int node = b * 512 + i;
        row_ptr[node] = gbase + off;
        deg[node] = d;
        dis[node] = (float)(1.0 / sqrt((double)(d + 1)));   // +1 self-loop
        cur[i] = off;
    }
    __syncthreads();
    bool inlds = (nb <= LCAP);
    for (int i = tid; i < nb; i += 256) {
        int2 e = ap[i];
        int p = atomicAdd(&cur[e.y], 1);
        if (inlds) stage[p] = e.x;
        else       csr_src[gbase + p] = e.x;
    }
    __syncthreads();
    if (inlds)
        for (int i = tid; i < nb; i += 256) csr_src[gbase + i] = stage[i];
}

// xw1s = dis[n] * (x @ W1). ONE NODE PER THREAD: per-lane x row (vector loads),
// all 64 output cols in registers. W row (64 floats) is wave-uniform -> SGPRs
// via s_load_dwordx16; FMAs read SGPR directly (1 SGPR src per VALU op: legal).
// Per k: 4 scalar loads amortized over 128 VALU cycles.
__global__ __launch_bounds__(256, 2) void k_mm1(const float* __restrict__ x, const float* __restrict__ W1,
                                                const float* __restrict__ dis, float* __restrict__ xw1s) {
    int n = blockIdx.x * 256 + threadIdx.x;
    const float4* xrow = (const float4*)(x + (size_t)n * IN_C);
    float acc[HID_C];
#pragma unroll
    for (int c = 0; c < HID_C; ++c) acc[c] = 0.f;
    float4 xq = xrow[0];
#pragma unroll 1
    for (int q = 0; q < IN_C / 4; ++q) {
        float4 xn = xrow[(q + 1) & (IN_C / 4 - 1)];   // prefetch next chunk (q=31 wraps, cached)
        const float* wrow = W1 + q * 4 * HID_C;       // wave-uniform -> SALU address
#pragma unroll
        for (int kk = 0; kk < 4; ++kk) {
            const float* wp = wrow + kk * HID_C;
            v16f w0, w1, w2, w3;
            asm volatile("s_load_dwordx16 %0, %1, 0x0"  : "=s"(w0) : "s"(wp));
            asm volatile("s_load_dwordx16 %0, %1, 0x40" : "=s"(w1) : "s"(wp));
            asm volatile("s_load_dwordx16 %0, %1, 0x80" : "=s"(w2) : "s"(wp));
            asm volatile("s_load_dwordx16 %0, %1, 0xc0" : "=s"(w3) : "s"(wp));
            // tie the wait to the loaded values: consumers can't be hoisted above it
            asm volatile("s_waitcnt lgkmcnt(0)" : "+s"(w0), "+s"(w1), "+s"(w2), "+s"(w3));
            float xk = (kk == 0) ? xq.x : (kk == 1) ? xq.y : (kk == 2) ? xq.z : xq.w;
#pragma unroll
            for (int c = 0; c < 16; ++c) {
                acc[c]      = fmaf(xk, w0[c], acc[c]);
                acc[c + 16] = fmaf(xk, w1[c], acc[c + 16]);
                acc[c + 32] = fmaf(xk, w2[c], acc[c + 32]);
                acc[c + 48] = fmaf(xk, w3[c], acc[c + 48]);
            }
        }
        xq = xn;
    }
    float dv = dis[n];
    float4* orow = (float4*)(xw1s + (size_t)n * HID_C);
#pragma unroll
    for (int c4 = 0; c4 < HID_C / 4; ++c4) {
        float4 o;
        o.x = acc[4 * c4 + 0] * dv;
        o.y = acc[4 * c4 + 1] * dv;
        o.z = acc[4 * c4 + 2] * dv;
        o.w = acc[4 * c4 + 3] * dv;
        orow[c4] = o;
    }
}

// layer-1 aggregation: one 64-lane wave per node; dis folded; 8 gather loads in flight.
__global__ __launch_bounds__(256) void k_agg1(const float* __restrict__ xw1s, const int* __restrict__ csr_src,
                                              const int* __restrict__ row_ptr, const int* __restrict__ deg,
                                              const float* __restrict__ dis, const float* __restrict__ b1,
                                              float* __restrict__ h) {
    int lane = threadIdx.x & 63;
    int v = blockIdx.x * 4 + (threadIdx.x >> 6);
    int start = row_ptr[v];
    int cnt = deg[v];
    float acc0 = xw1s[(size_t)v * HID_C + lane];   // self-loop term (already dis-scaled)
    float acc1 = 0.f, acc2 = 0.f, acc3 = 0.f;
    for (int base = 0; base < cnt; base += 64) {
        int mcnt = min(64, cnt - base);
        int sj = 0;
        if (lane < mcnt) sj = csr_src[start + base + lane];
        int j = 0;
        for (; j + 8 <= mcnt; j += 8) {
            int s0 = __shfl(sj, j + 0), s1 = __shfl(sj, j + 1);
            int s2 = __shfl(sj, j + 2), s3 = __shfl(sj, j + 3);
            int s4 = __shfl(sj, j + 4), s5 = __shfl(sj, j + 5);
            int s6 = __shfl(sj, j + 6), s7 = __shfl(sj, j + 7);
            float v0 = xw1s[(size_t)s0 * HID_C + lane];
            float v1 = xw1s[(size_t)s1 * HID_C + lane];
            float v2 = xw1s[(size_t)s2 * HID_C + lane];
            float v3 = xw1s[(size_t)s3 * HID_C + lane];
            float v4 = xw1s[(size_t)s4 * HID_C + lane];
            float v5 = xw1s[(size_t)s5 * HID_C + lane];
            float v6 = xw1s[(size_t)s6 * HID_C + lane];
            float v7 = xw1s[(size_t)s7 * HID_C + lane];
            acc0 += v0 + v4;
            acc1 += v1 + v5;
            acc2 += v2 + v6;
            acc3 += v3 + v7;
        }
        for (; j < mcnt; ++j) {
            int s = __shfl(sj, j);
            acc0 += xw1s[(size_t)s * HID_C + lane];
        }
    }
    float o = fmaf(dis[v], (acc0 + acc1) + (acc2 + acc3), b1[lane]);
    h[(size_t)v * HID_C + lane] = fmaxf(o, 0.f);   // ReLU fused
}

// xw2s = dis[n] * (h @ W2). Same one-node-per-thread structure; K=64, 32 cols.
__global__ __launch_bounds__(256, 2) void k_mm2(const float* __restrict__ h, const float* __restrict__ W2,
                                                const float* __restrict__ dis, float* __restrict__ xw2s) {
    int n = blockIdx.x * 256 + threadIdx.x;
    const float4* hrow = (const float4*)(h + (size_t)n * HID_C);
    float acc[OUT_C];
#pragma unroll
    for (int c = 0; c < OUT_C; ++c) acc[c] = 0.f;
    float4 xq = hrow[0];
#pragma unroll 1
    for (int q = 0; q < HID_C / 4; ++q) {
        float4 xn = hrow[(q + 1) & (HID_C / 4 - 1)];
        const float* wrow = W2 + q * 4 * OUT_C;
#pragma unroll
        for (int kk = 0; kk < 4; ++kk) {
            const float* wp = wrow + kk * OUT_C;
            v16f w0, w1;
            asm volatile("s_load_dwordx16 %0, %1, 0x0"  : "=s"(w0) : "s"(wp));
            asm volatile("s_load_dwordx16 %0, %1, 0x40" : "=s"(w1) : "s"(wp));
            asm volatile("s_waitcnt lgkmcnt(0)" : "+s"(w0), "+s"(w1));
            float xk = (kk == 0) ? xq.x : (kk == 1) ? xq.y : (kk == 2) ? xq.z : xq.w;
#pragma unroll
            for (int c = 0; c < 16; ++c) {
                acc[c]      = fmaf(xk, w0[c], acc[c]);
                acc[c + 16] = fmaf(xk, w1[c], acc[c + 16]);
            }
        }
        xq = xn;
    }
    float dv = dis[n];
    float4* orow = (float4*)(xw2s + (size_t)n * OUT_C);
#pragma unroll
    for (int c4 = 0; c4 < OUT_C / 4; ++c4) {
        float4 o;
        o.x = acc[4 * c4 + 0] * dv;
        o.y = acc[4 * c4 + 1] * dv;
        o.z = acc[4 * c4 + 2] * dv;
        o.w = acc[4 * c4 + 3] * dv;
        orow[c4] = o;
    }
}

// layer-2 aggregation: 32-lane group per node; dis folded; 8 gather loads in flight.
__global__ __launch_bounds__(256) void k_agg2(const float* __restrict__ xw2s, const int* __restrict__ csr_src,
                                              const int* __restrict__ row_ptr, const int* __restrict__ deg,
                                              const float* __restrict__ dis, const float* __restrict__ b2,
                                              float* __restrict__ out2) {
    int lane = threadIdx.x & 31;
    int v = blockIdx.x * 8 + (threadIdx.x >> 5);
    int start = row_ptr[v];
    int cnt = deg[v];
    float acc0 = xw2s[(size_t)v * OUT_C + lane];   // self-loop term
    float acc1 = 0.f, acc2 = 0.f, acc3 = 0.f;
    for (int base = 0; base < cnt; base += 32) {
        int mcnt = min(32, cnt - base);
        int sj = 0;
        if (lane < mcnt) sj = csr_src[start + base + lane];
        int j = 0;
        for (; j + 8 <= mcnt; j += 8) {
            int s0 = __shfl(sj, j + 0, 32), s1 = __shfl(sj, j + 1, 32);
            int s2 = __shfl(sj, j + 2, 32), s3 = __shfl(sj, j + 3, 32);
            int s4 = __shfl(sj, j + 4, 32), s5 = __shfl(sj, j + 5, 32);
            int s6 = __shfl(sj, j + 6, 32), s7 = __shfl(sj, j + 7, 32);
            float v0 = xw2s[(size_t)s0 * OUT_C + lane];
            float v1 = xw2s[(size_t)s1 * OUT_C + lane];
            float v2 = xw2s[(size_t)s2 * OUT_C + lane];
            float v3 = xw2s[(size_t)s3 * OUT_C + lane];
            float v4 = xw2s[(size_t)s4 * OUT_C + lane];
            float v5 = xw2s[(size_t)s5 * OUT_C + lane];
            float v6 = xw2s[(size_t)s6 * OUT_C + lane];
            float v7 = xw2s[(size_t)s7 * OUT_C + lane];
            acc0 += v0 + v4;
            acc1 += v1 + v5;
            acc2 += v2 + v6;
            acc3 += v3 + v7;
        }
        for (; j < mcnt; ++j) {
            int s = __shfl(sj, j, 32);
            acc0 += xw2s[(size_t)s * OUT_C + lane];
        }
    }
    out2[(size_t)v * OUT_C + lane] = fmaf(dis[v], (acc0 + acc1) + (acc2 + acc3), b2[lane]);
}

// per-graph top-30 by channel 31 (desc, stable), emit [512, 30*32] f32.
__global__ __launch_bounds__(256) void k_sort(const float* __restrict__ out2, float* __restrict__ out) {
    __shared__ float keys[NPG];
    __shared__ int order[TOPK];
    int g = blockIdx.x;
    int tid = threadIdx.x;
    int base = g * NPG;
    if (tid < NPG) keys[tid] = out2[(size_t)(base + tid) * OUT_C + (OUT_C - 1)];
    __syncthreads();
    if (tid < NPG) {
        float my = keys[tid];
        int r = 0;
        for (int j = 0; j < NPG; ++j) {
            float kj = keys[j];
            r += (kj > my) || (kj == my && j < tid);
        }
        if (r < TOPK) order[r] = tid;
    }
    __syncthreads();
    for (int idx = tid; idx < TOPK * OUT_C; idx += 256) {
        int r = idx >> 5;
        int c = idx & 31;
        int n = order[r];
        out[g * (TOPK * OUT_C) + idx] = out2[(size_t)(base + n) * OUT_C + c];
    }
}

extern "C" void kernel_launch(void* const* d_in, const int* in_sizes, int n_in,
                              void* d_out, int out_size, void* d_ws, size_t ws_size,
                              hipStream_t stream) {
    const float* x  = (const float*)d_in[0];
    const int*   ei = (const int*)d_in[1];
    const int*   srcp = ei;             // edge_index[0]
    const int*   dstp = ei + N_EDGES;   // edge_index[1]
    // d_in[2] (batch) unused: graphs are contiguous 196-node blocks.
    const float* W1 = (const float*)d_in[3];
    const float* b1 = (const float*)d_in[4];
    const float* W2 = (const float*)d_in[5];
    const float* b2 = (const float*)d_in[6];
    float* out = (float*)d_out;

    char* w = (char*)d_ws;
    int*    deg      = (int*)(w + OFF_DEG);
    int*    row_ptr  = (int*)(w + OFF_ROWPTR);
    float*  dis      = (float*)(w + OFF_DIS);
    int*    bcnt     = (int*)(w + OFF_BCNT);
    int*    bbase    = (int*)(w + OFF_BBASE);
    int2*   arena    = (int2*)(w + OFF_ARENA);
    int*    csr_src  = (int*)(w + OFF_CSR);
    float*  xw1s     = (float*)(w + OFF_XW1);
    float*  h        = (float*)(w + OFF_H);
    float*  xw2s     = (float*)(w + OFF_XW2);
    float*  out2     = (float*)(w + OFF_OUT2);   // aliases arena (dead after k_build)

    hipMemsetAsync(bcnt, 0, NB * sizeof(int), stream);
    k_bucket<<<N_EDGES / (256 * 8), 256, 0, stream>>>(srcp, dstp, bcnt, arena);
    k_bscan <<<1, 256, 0, stream>>>(bcnt, bbase);
    k_build <<<NB, 256, 0, stream>>>(arena, bcnt, bbase, row_ptr, deg, dis, csr_src);
    k_mm1   <<<N_NODES / 256, 256, 0, stream>>>(x, W1, dis, xw1s);
    k_agg1  <<<N_NODES / 4, 256, 0, stream>>>(xw1s, csr_src, row_ptr, deg, dis, b1, h);
    k_mm2   <<<N_NODES / 256, 256, 0, stream>>>(h, W2, dis, xw2s);
    k_agg2  <<<N_NODES / 8, 256, 0, stream>>>(xw2s, csr_src, row_ptr, deg, dis, b2, out2);
    k_sort  <<<NUM_GRAPHS, 256, 0, stream>>>(out2, out);
}

// Round 10
// 235.131 us; speedup vs baseline: 1.9641x; 1.0422x over previous
//
#include <hip/hip_runtime.h>

#define N_NODES   100352
#define N_EDGES   1605632
#define IN_C      128
#define HID_C     64
#define OUT_C     32
#define NUM_GRAPHS 512
#define NPG       196
#define TOPK      30

#define NB        196     // buckets = dst>>9 (512 nodes each; 196*512 = 100352)
#define BCAP      10240   // arena capacity per bucket (E[nb]=8192, sigma~90)
#define LCAP      10240   // LDS staging capacity in k_build (40 KB)

typedef float v16f __attribute__((ext_vector_type(16)));

// ws layout (bytes)
#define OFF_DEG     0u          // int[N]
#define OFF_ROWPTR  401408u     // int[N]
#define OFF_DIS     802816u     // float[N]
#define OFF_BCNT    1204224u    // int[NB]
#define OFF_BBASE   1205248u    // int[NB]
#define OFF_ARENA   1206272u    // int2[NB*BCAP] = 16,056,320 B  (dead after k_build)
#define OFF_OUT2    1206272u    // float[N*32] = 12,845,056 B  -- aliases arena
#define OFF_CSR     17262592u   // int[E]
#define OFF_XW1     23685120u   // float[N*64]  (dis-scaled)
#define OFF_H       49375232u   // float[N*64]
#define OFF_XW2     75065344u   // float[N*32]  (dis-scaled)

// Pass 1: bucketize edges. LDS histogram -> one global atomic per (block,bucket)
// -> writes to 196 sequential arena windows (sectors fill -> no write amplification).
__global__ __launch_bounds__(256) void k_bucket(const int* __restrict__ src, const int* __restrict__ dst,
                                                int* __restrict__ bucket_cnt, int2* __restrict__ arena) {
    __shared__ int hist[NB];
    __shared__ int cur[NB];
    int tid = threadIdx.x;
    for (int i = tid; i < NB; i += 256) hist[i] = 0;
    __syncthreads();
    int e0 = (blockIdx.x * 256 + tid) * 8;       // 8 edges per thread
    int4 sa = ((const int4*)src)[e0 / 4], sb = ((const int4*)src)[e0 / 4 + 1];
    int4 da = ((const int4*)dst)[e0 / 4], db = ((const int4*)dst)[e0 / 4 + 1];
    int es[8] = {sa.x, sa.y, sa.z, sa.w, sb.x, sb.y, sb.z, sb.w};
    int ed[8] = {da.x, da.y, da.z, da.w, db.x, db.y, db.z, db.w};
    int eb[8];
#pragma unroll
    for (int j = 0; j < 8; ++j) { eb[j] = ed[j] >> 9; atomicAdd(&hist[eb[j]], 1); }
    __syncthreads();
    for (int i = tid; i < NB; i += 256) {
        int c = hist[i];
        cur[i] = (c > 0) ? atomicAdd(&bucket_cnt[i], c) : 0;
    }
    __syncthreads();
#pragma unroll
    for (int j = 0; j < 8; ++j) {
        int p = atomicAdd(&cur[eb[j]], 1);
        if (p < BCAP) arena[(size_t)eb[j] * BCAP + p] = make_int2(es[j], ed[j] & 511);
    }
}

// Exclusive scan of 196 bucket counts.
__global__ __launch_bounds__(256) void k_bscan(const int* __restrict__ bucket_cnt, int* __restrict__ bucket_base) {
    __shared__ int s[256];
    int t = threadIdx.x;
    int v = (t < NB) ? bucket_cnt[t] : 0;
    s[t] = v;
    __syncthreads();
    for (int o = 1; o < 256; o <<= 1) {
        int a = (t >= o) ? s[t - o] : 0;
        __syncthreads();
        s[t] += a;
        __syncthreads();
    }
    if (t < NB) bucket_base[t] = s[t] - v;
}

// Pass 2: per bucket (512 nodes): deg + row_ptr + dis via LDS, CSR via LDS staging.
__global__ __launch_bounds__(256) void k_build(const int2* __restrict__ arena, const int* __restrict__ bucket_cnt,
                                               const int* __restrict__ bucket_base, int* __restrict__ row_ptr,
                                               int* __restrict__ deg, float* __restrict__ dis,
                                               int* __restrict__ csr_src) {
    __shared__ int dloc[512];
    __shared__ int sc[512];
    __shared__ int cur[512];
    __shared__ int stage[LCAP];
    int b = blockIdx.x;
    int tid = threadIdx.x;
    int nb = min(bucket_cnt[b], BCAP);
    int gbase = bucket_base[b];
    const int2* ap = arena + (size_t)b * BCAP;
    for (int i = tid; i < 512; i += 256) dloc[i] = 0;
    __syncthreads();
    for (int i = tid; i < nb; i += 256) {
        int2 e = ap[i];
        atomicAdd(&dloc[e.y], 1);
    }
    __syncthreads();
    for (int i = tid; i < 512; i += 256) sc[i] = dloc[i];
    __syncthreads();
    for (int o = 1; o < 512; o <<= 1) {        // Hillis-Steele inclusive scan, 512 elems
        int i0 = tid, i1 = tid + 256;
        int v0 = (i0 >= o) ? sc[i0 - o] : 0;
        int v1 = (i1 >= o) ? sc[i1 - o] : 0;
        __syncthreads();
        sc[i0] += v0;
        sc[i1] += v1;
        __syncthreads();
    }
    for (int i = tid; i < 512; i += 256) {
        int d = dloc[i];
        int off = sc[i] - d;                   // exclusive prefix
        int node = b * 512 + i;
        row_ptr[node] = gbase + off;
        deg[node] = d;
        dis[node] = (float)(1.0 / sqrt((double)(d + 1)));   // +1 self-loop
        cur[i] = off;
    }
    __syncthreads();
    bool inlds = (nb <= LCAP);
    for (int i = tid; i < nb; i += 256) {
        int2 e = ap[i];
        int p = atomicAdd(&cur[e.y], 1);
        if (inlds) stage[p] = e.x;
        else       csr_src[gbase + p] = e.x;
    }
    __syncthreads();
    if (inlds)
        for (int i = tid; i < nb; i += 256) csr_src[gbase + i] = stage[i];
}

// xw1s = dis[n] * (x @ W1). One node per thread, COL-SPLIT 2-way:
// block = 128 nodes x 2 col-halves; ch is wave-uniform (tid>>7 constant per wave)
// but threadIdx-derived -> readfirstlane pins it to SGPR so W addresses stay scalar.
__global__ __launch_bounds__(256) void k_mm1(const float* __restrict__ x, const float* __restrict__ W1,
                                             const float* __restrict__ dis, float* __restrict__ xw1s) {
    int tid = threadIdx.x;
    int n = blockIdx.x * 128 + (tid & 127);
    int ch = __builtin_amdgcn_readfirstlane((tid >> 7) * 32);   // wave-uniform col half -> SGPR
    const float4* xrow = (const float4*)(x + (size_t)n * IN_C);
    float acc[32];
#pragma unroll
    for (int c = 0; c < 32; ++c) acc[c] = 0.f;
    float4 xq = xrow[0];
#pragma unroll 1
    for (int q = 0; q < IN_C / 4; ++q) {
        float4 xn = xrow[(q + 1) & (IN_C / 4 - 1)];   // prefetch next chunk
        const float* wrow = W1 + q * 4 * HID_C + ch;  // scalar address chain
#pragma unroll
        for (int kk = 0; kk < 4; ++kk) {
            const float* wp = wrow + kk * HID_C;
            v16f w0, w1;
            asm volatile("s_load_dwordx16 %0, %1, 0x0"  : "=s"(w0) : "s"(wp));
            asm volatile("s_load_dwordx16 %0, %1, 0x40" : "=s"(w1) : "s"(wp));
            asm volatile("s_waitcnt lgkmcnt(0)" : "+s"(w0), "+s"(w1));
            float xk = (kk == 0) ? xq.x : (kk == 1) ? xq.y : (kk == 2) ? xq.z : xq.w;
#pragma unroll
            for (int c = 0; c < 16; ++c) {
                acc[c]      = fmaf(xk, w0[c], acc[c]);
                acc[c + 16] = fmaf(xk, w1[c], acc[c + 16]);
            }
        }
        xq = xn;
    }
    float dv = dis[n];
    float4* orow = (float4*)(xw1s + (size_t)n * HID_C + ch);
#pragma unroll
    for (int c4 = 0; c4 < 8; ++c4) {
        float4 o;
        o.x = acc[4 * c4 + 0] * dv;
        o.y = acc[4 * c4 + 1] * dv;
        o.z = acc[4 * c4 + 2] * dv;
        o.w = acc[4 * c4 + 3] * dv;
        orow[c4] = o;
    }
}

// layer-1 aggregation: one 64-lane wave per node; dis folded; 8 gather loads in flight.
__global__ __launch_bounds__(256) void k_agg1(const float* __restrict__ xw1s, const int* __restrict__ csr_src,
                                              const int* __restrict__ row_ptr, const int* __restrict__ deg,
                                              const float* __restrict__ dis, const float* __restrict__ b1,
                                              float* __restrict__ h) {
    int lane = threadIdx.x & 63;
    int v = blockIdx.x * 4 + (threadIdx.x >> 6);
    int start = row_ptr[v];
    int cnt = deg[v];
    float acc0 = xw1s[(size_t)v * HID_C + lane];   // self-loop term (already dis-scaled)
    float acc1 = 0.f, acc2 = 0.f, acc3 = 0.f;
    for (int base = 0; base < cnt; base += 64) {
        int mcnt = min(64, cnt - base);
        int sj = 0;
        if (lane < mcnt) sj = csr_src[start + base + lane];
        int j = 0;
        for (; j + 8 <= mcnt; j += 8) {
            int s0 = __shfl(sj, j + 0), s1 = __shfl(sj, j + 1);
            int s2 = __shfl(sj, j + 2), s3 = __shfl(sj, j + 3);
            int s4 = __shfl(sj, j + 4), s5 = __shfl(sj, j + 5);
            int s6 = __shfl(sj, j + 6), s7 = __shfl(sj, j + 7);
            float v0 = xw1s[(size_t)s0 * HID_C + lane];
            float v1 = xw1s[(size_t)s1 * HID_C + lane];
            float v2 = xw1s[(size_t)s2 * HID_C + lane];
            float v3 = xw1s[(size_t)s3 * HID_C + lane];
            float v4 = xw1s[(size_t)s4 * HID_C + lane];
            float v5 = xw1s[(size_t)s5 * HID_C + lane];
            float v6 = xw1s[(size_t)s6 * HID_C + lane];
            float v7 = xw1s[(size_t)s7 * HID_C + lane];
            acc0 += v0 + v4;
            acc1 += v1 + v5;
            acc2 += v2 + v6;
            acc3 += v3 + v7;
        }
        for (; j < mcnt; ++j) {
            int s = __shfl(sj, j);
            acc0 += xw1s[(size_t)s * HID_C + lane];
        }
    }
    float o = fmaf(dis[v], (acc0 + acc1) + (acc2 + acc3), b1[lane]);
    h[(size_t)v * HID_C + lane] = fmaxf(o, 0.f);   // ReLU fused
}

// xw2s = dis[n] * (h @ W2). One node per thread, col-split 2-way (16 cols each).
__global__ __launch_bounds__(256) void k_mm2(const float* __restrict__ h, const float* __restrict__ W2,
                                             const float* __restrict__ dis, float* __restrict__ xw2s) {
    int tid = threadIdx.x;
    int n = blockIdx.x * 128 + (tid & 127);
    int ch = __builtin_amdgcn_readfirstlane((tid >> 7) * 16);   // wave-uniform col half -> SGPR
    const float4* hrow = (const float4*)(h + (size_t)n * HID_C);
    float acc[16];
#pragma unroll
    for (int c = 0; c < 16; ++c) acc[c] = 0.f;
    float4 xq = hrow[0];
#pragma unroll 1
    for (int q = 0; q < HID_C / 4; ++q) {
        float4 xn = hrow[(q + 1) & (HID_C / 4 - 1)];
        const float* wrow = W2 + q * 4 * OUT_C + ch;
#pragma unroll
        for (int kk = 0; kk < 4; ++kk) {
            const float* wp = wrow + kk * OUT_C;
            v16f w0;
            asm volatile("s_load_dwordx16 %0, %1, 0x0" : "=s"(w0) : "s"(wp));
            asm volatile("s_waitcnt lgkmcnt(0)" : "+s"(w0));
            float xk = (kk == 0) ? xq.x : (kk == 1) ? xq.y : (kk == 2) ? xq.z : xq.w;
#pragma unroll
            for (int c = 0; c < 16; ++c)
                acc[c] = fmaf(xk, w0[c], acc[c]);
        }
        xq = xn;
    }
    float dv = dis[n];
    float4* orow = (float4*)(xw2s + (size_t)n * OUT_C + ch);
#pragma unroll
    for (int c4 = 0; c4 < 4; ++c4) {
        float4 o;
        o.x = acc[4 * c4 + 0] * dv;
        o.y = acc[4 * c4 + 1] * dv;
        o.z = acc[4 * c4 + 2] * dv;
        o.w = acc[4 * c4 + 3] * dv;
        orow[c4] = o;
    }
}

// layer-2 aggregation: 32-lane group per node; dis folded; 8 gather loads in flight.
__global__ __launch_bounds__(256) void k_agg2(const float* __restrict__ xw2s, const int* __restrict__ csr_src,
                                              const int* __restrict__ row_ptr, const int* __restrict__ deg,
                                              const float* __restrict__ dis, const float* __restrict__ b2,
                                              float* __restrict__ out2) {
    int lane = threadIdx.x & 31;
    int v = blockIdx.x * 8 + (threadIdx.x >> 5);
    int start = row_ptr[v];
    int cnt = deg[v];
    float acc0 = xw2s[(size_t)v * OUT_C + lane];   // self-loop term
    float acc1 = 0.f, acc2 = 0.f, acc3 = 0.f;
    for (int base = 0; base < cnt; base += 32) {
        int mcnt = min(32, cnt - base);
        int sj = 0;
        if (lane < mcnt) sj = csr_src[start + base + lane];
        int j = 0;
        for (; j + 8 <= mcnt; j += 8) {
            int s0 = __shfl(sj, j + 0, 32), s1 = __shfl(sj, j + 1, 32);
            int s2 = __shfl(sj, j + 2, 32), s3 = __shfl(sj, j + 3, 32);
            int s4 = __shfl(sj, j + 4, 32), s5 = __shfl(sj, j + 5, 32);
            int s6 = __shfl(sj, j + 6, 32), s7 = __shfl(sj, j + 7, 32);
            float v0 = xw2s[(size_t)s0 * OUT_C + lane];
            float v1 = xw2s[(size_t)s1 * OUT_C + lane];
            float v2 = xw2s[(size_t)s2 * OUT_C + lane];
            float v3 = xw2s[(size_t)s3 * OUT_C + lane];
            float v4 = xw2s[(size_t)s4 * OUT_C + lane];
            float v5 = xw2s[(size_t)s5 * OUT_C + lane];
            float v6 = xw2s[(size_t)s6 * OUT_C + lane];
            float v7 = xw2s[(size_t)s7 * OUT_C + lane];
            acc0 += v0 + v4;
            acc1 += v1 + v5;
            acc2 += v2 + v6;
            acc3 += v3 + v7;
        }
        for (; j < mcnt; ++j) {
            int s = __shfl(sj, j, 32);
            acc0 += xw2s[(size_t)s * OUT_C + lane];
        }
    }
    out2[(size_t)v * OUT_C + lane] = fmaf(dis[v], (acc0 + acc1) + (acc2 + acc3), b2[lane]);
}

// per-graph top-30 by channel 31 (desc, stable), emit [512, 30*32] f32.
__global__ __launch_bounds__(256) void k_sort(const float* __restrict__ out2, float* __restrict__ out) {
    __shared__ float keys[NPG];
    __shared__ int order[TOPK];
    int g = blockIdx.x;
    int tid = threadIdx.x;
    int base = g * NPG;
    if (tid < NPG) keys[tid] = out2[(size_t)(base + tid) * OUT_C + (OUT_C - 1)];
    __syncthreads();
    if (tid < NPG) {
        float my = keys[tid];
        int r = 0;
        for (int j = 0; j < NPG; ++j) {
            float kj = keys[j];
            r += (kj > my) || (kj == my && j < tid);
        }
        if (r < TOPK) order[r] = tid;
    }
    __syncthreads();
    for (int idx = tid; idx < TOPK * OUT_C; idx += 256) {
        int r = idx >> 5;
        int c = idx & 31;
        int n = order[r];
        out[g * (TOPK * OUT_C) + idx] = out2[(size_t)(base + n) * OUT_C + c];
    }
}

extern "C" void kernel_launch(void* const* d_in, const int* in_sizes, int n_in,
                              void* d_out, int out_size, void* d_ws, size_t ws_size,
                              hipStream_t stream) {
    const float* x  = (const float*)d_in[0];
    const int*   ei = (const int*)d_in[1];
    const int*   srcp = ei;             // edge_index[0]
    const int*   dstp = ei + N_EDGES;   // edge_index[1]
    // d_in[2] (batch) unused: graphs are contiguous 196-node blocks.
    const float* W1 = (const float*)d_in[3];
    const float* b1 = (const float*)d_in[4];
    const float* W2 = (const float*)d_in[5];
    const float* b2 = (const float*)d_in[6];
    float* out = (float*)d_out;

    char* w = (char*)d_ws;
    int*    deg      = (int*)(w + OFF_DEG);
    int*    row_ptr  = (int*)(w + OFF_ROWPTR);
    float*  dis      = (float*)(w + OFF_DIS);
    int*    bcnt     = (int*)(w + OFF_BCNT);
    int*    bbase    = (int*)(w + OFF_BBASE);
    int2*   arena    = (int2*)(w + OFF_ARENA);
    int*    csr_src  = (int*)(w + OFF_CSR);
    float*  xw1s     = (float*)(w + OFF_XW1);
    float*  h        = (float*)(w + OFF_H);
    float*  xw2s     = (float*)(w + OFF_XW2);
    float*  out2     = (float*)(w + OFF_OUT2);   // aliases arena (dead after k_build)

    hipMemsetAsync(bcnt, 0, NB * sizeof(int), stream);
    k_bucket<<<N_EDGES / (256 * 8), 256, 0, stream>>>(srcp, dstp, bcnt, arena);
    k_bscan <<<1, 256, 0, stream>>>(bcnt, bbase);
    k_build <<<NB, 256, 0, stream>>>(arena, bcnt, bbase, row_ptr, deg, dis, csr_src);
    k_mm1   <<<N_NODES / 128, 256, 0, stream>>>(x, W1, dis, xw1s);
    k_agg1  <<<N_NODES / 4, 256, 0, stream>>>(xw1s, csr_src, row_ptr, deg, dis, b1, h);
    k_mm2   <<<N_NODES / 128, 256, 0, stream>>>(h, W2, dis, xw2s);
    k_agg2  <<<N_NODES / 8, 256, 0, stream>>>(xw2s, csr_src, row_ptr, deg, dis, b2, out2);
    k_sort  <<<NUM_GRAPHS, 256, 0, stream>>>(out2, out);
}

// Round 11
// 226.468 us; speedup vs baseline: 2.0392x; 1.0382x over previous
//
#include <hip/hip_runtime.h>

#define N_NODES   100352
#define N_EDGES   1605632
#define IN_C      128
#define HID_C     64
#define OUT_C     32
#define NUM_GRAPHS 512
#define NPG       196
#define TOPK      30

#define NB        196     // buckets = dst>>9 (512 nodes each; 196*512 = 100352)
#define BCAP      10240   // arena capacity per bucket (E[nb]=8192, sigma~90)
#define LCAP      10240   // LDS staging capacity in k_build (40 KB)

typedef float v16f __attribute__((ext_vector_type(16)));

// ws layout (bytes)
#define OFF_DEG     0u          // int[N]
#define OFF_ROWPTR  401408u     // int[N]
#define OFF_DIS     802816u     // float[N]
#define OFF_BCNT    1204224u    // int[NB]
#define OFF_BBASE   1205248u    // int[NB]
#define OFF_ARENA   1206272u    // int[NB*BCAP] = 8,028,160 B (packed; dead after k_build)
#define OFF_OUT2    1206272u    // float[N*32] = 12,845,056 B -- aliases arena slot (16 MB reserved)
#define OFF_CSR     17262592u   // int[E]
#define OFF_XW1     23685120u   // float[N*64]  (dis-scaled)
#define OFF_XW2     75065344u   // float[N*32]  (dis-scaled)

// Pass 1: bucketize edges, packed (src<<9 | dst&511) -- src < 2^17.
__global__ __launch_bounds__(256) void k_bucket(const int* __restrict__ src, const int* __restrict__ dst,
                                                int* __restrict__ bucket_cnt, int* __restrict__ arena) {
    __shared__ int hist[NB];
    __shared__ int cur[NB];
    int tid = threadIdx.x;
    for (int i = tid; i < NB; i += 256) hist[i] = 0;
    __syncthreads();
    int e0 = (blockIdx.x * 256 + tid) * 8;       // 8 edges per thread
    int4 sa = ((const int4*)src)[e0 / 4], sb = ((const int4*)src)[e0 / 4 + 1];
    int4 da = ((const int4*)dst)[e0 / 4], db = ((const int4*)dst)[e0 / 4 + 1];
    int es[8] = {sa.x, sa.y, sa.z, sa.w, sb.x, sb.y, sb.z, sb.w};
    int ed[8] = {da.x, da.y, da.z, da.w, db.x, db.y, db.z, db.w};
    int eb[8];
#pragma unroll
    for (int j = 0; j < 8; ++j) { eb[j] = ed[j] >> 9; atomicAdd(&hist[eb[j]], 1); }
    __syncthreads();
    for (int i = tid; i < NB; i += 256) {
        int c = hist[i];
        cur[i] = (c > 0) ? atomicAdd(&bucket_cnt[i], c) : 0;
    }
    __syncthreads();
#pragma unroll
    for (int j = 0; j < 8; ++j) {
        int p = atomicAdd(&cur[eb[j]], 1);
        if (p < BCAP) arena[(size_t)eb[j] * BCAP + p] = (es[j] << 9) | (ed[j] & 511);
    }
}

// Exclusive scan of 196 bucket counts.
__global__ __launch_bounds__(256) void k_bscan(const int* __restrict__ bucket_cnt, int* __restrict__ bucket_base) {
    __shared__ int s[256];
    int t = threadIdx.x;
    int v = (t < NB) ? bucket_cnt[t] : 0;
    s[t] = v;
    __syncthreads();
    for (int o = 1; o < 256; o <<= 1) {
        int a = (t >= o) ? s[t - o] : 0;
        __syncthreads();
        s[t] += a;
        __syncthreads();
    }
    if (t < NB) bucket_base[t] = s[t] - v;
}

// Pass 2: per bucket (512 nodes): deg + row_ptr + dis via LDS, CSR via LDS staging.
__global__ __launch_bounds__(256) void k_build(const int* __restrict__ arena, const int* __restrict__ bucket_cnt,
                                               const int* __restrict__ bucket_base, int* __restrict__ row_ptr,
                                               int* __restrict__ deg, float* __restrict__ dis,
                                               int* __restrict__ csr_src) {
    __shared__ int dloc[512];
    __shared__ int sc[512];
    __shared__ int cur[512];
    __shared__ int stage[LCAP];
    int b = blockIdx.x;
    int tid = threadIdx.x;
    int nb = min(bucket_cnt[b], BCAP);
    int gbase = bucket_base[b];
    const int* ap = arena + (size_t)b * BCAP;
    for (int i = tid; i < 512; i += 256) dloc[i] = 0;
    __syncthreads();
    for (int i = tid; i < nb; i += 256) {
        int e = ap[i];
        atomicAdd(&dloc[e & 511], 1);
    }
    __syncthreads();
    for (int i = tid; i < 512; i += 256) sc[i] = dloc[i];
    __syncthreads();
    for (int o = 1; o < 512; o <<= 1) {        // Hillis-Steele inclusive scan, 512 elems
        int i0 = tid, i1 = tid + 256;
        int v0 = (i0 >= o) ? sc[i0 - o] : 0;
        int v1 = (i1 >= o) ? sc[i1 - o] : 0;
        __syncthreads();
        sc[i0] += v0;
        sc[i1] += v1;
        __syncthreads();
    }
    for (int i = tid; i < 512; i += 256) {
        int d = dloc[i];
        int off = sc[i] - d;                   // exclusive prefix
        int node = b * 512 + i;
        row_ptr[node] = gbase + off;
        deg[node] = d;
        dis[node] = (float)(1.0 / sqrt((double)(d + 1)));   // +1 self-loop
        cur[i] = off;
    }
    __syncthreads();
    bool inlds = (nb <= LCAP);
    for (int i = tid; i < nb; i += 256) {
        int e = ap[i];
        int p = atomicAdd(&cur[e & 511], 1);
        int sv = ((unsigned)e) >> 9;
        if (inlds) stage[p] = sv;
        else       csr_src[gbase + p] = sv;
    }
    __syncthreads();
    if (inlds)
        for (int i = tid; i < nb; i += 256) csr_src[gbase + i] = stage[i];
}

// xw1s = dis[n] * (x @ W1). One node per thread, COL-SPLIT 4-way:
// block = 64 nodes x 4 col-quarters; ch wave-uniform -> readfirstlane -> SGPR.
// Per q: 4 batched s_load_dwordx16 (one per k row), ONE drain, 64 FMAs.
__global__ __launch_bounds__(256) void k_mm1(const float* __restrict__ x, const float* __restrict__ W1,
                                             const float* __restrict__ dis, float* __restrict__ xw1s) {
    int tid = threadIdx.x;
    int n = blockIdx.x * 64 + (tid & 63);
    int ch = __builtin_amdgcn_readfirstlane((tid >> 6) * 16);   // col quarter -> SGPR
    const float4* xrow = (const float4*)(x + (size_t)n * IN_C);
    float acc[16];
#pragma unroll
    for (int c = 0; c < 16; ++c) acc[c] = 0.f;
    float4 xq = xrow[0];
#pragma unroll 1
    for (int q = 0; q < IN_C / 4; ++q) {
        float4 xn = xrow[(q + 1) & (IN_C / 4 - 1)];   // prefetch next chunk
        const float* wp = W1 + q * 4 * HID_C + ch;    // scalar address chain
        v16f w0, w1, w2, w3;
        asm volatile("s_load_dwordx16 %0, %1, 0x0"   : "=s"(w0) : "s"(wp));
        asm volatile("s_load_dwordx16 %0, %1, 0x100" : "=s"(w1) : "s"(wp));
        asm volatile("s_load_dwordx16 %0, %1, 0x200" : "=s"(w2) : "s"(wp));
        asm volatile("s_load_dwordx16 %0, %1, 0x300" : "=s"(w3) : "s"(wp));
        asm volatile("s_waitcnt lgkmcnt(0)" : "+s"(w0), "+s"(w1), "+s"(w2), "+s"(w3));
#pragma unroll
        for (int c = 0; c < 16; ++c) {
            acc[c] = fmaf(xq.x, w0[c], acc[c]);
            acc[c] = fmaf(xq.y, w1[c], acc[c]);
            acc[c] = fmaf(xq.z, w2[c], acc[c]);
            acc[c] = fmaf(xq.w, w3[c], acc[c]);
        }
        xq = xn;
    }
    float dv = dis[n];
    float4* orow = (float4*)(xw1s + (size_t)n * HID_C + ch);
#pragma unroll
    for (int c4 = 0; c4 < 4; ++c4) {
        float4 o;
        o.x = acc[4 * c4 + 0] * dv;
        o.y = acc[4 * c4 + 1] * dv;
        o.z = acc[4 * c4 + 2] * dv;
        o.w = acc[4 * c4 + 3] * dv;
        orow[c4] = o;
    }
}

// FUSED layer-1 aggregation + layer-2 GEMM:
// wave per node v computes h[v] (lane = channel, in-register), then
// xw2s[v] = dis[v] * (h[v] @ W2) in-wave: 32 bpermute broadcasts of h +
// 32 conflict-free LDS reads of W2 + shfl_xor(32) half-merge. h never
// touches global memory; mm2 kernel eliminated.
__global__ __launch_bounds__(256) void k_agg1(const float* __restrict__ xw1s, const int* __restrict__ csr_src,
                                              const int* __restrict__ row_ptr, const int* __restrict__ deg,
                                              const float* __restrict__ dis, const float* __restrict__ b1,
                                              const float* __restrict__ W2, float* __restrict__ xw2s) {
    __shared__ float w2lds[HID_C * OUT_C];   // 8 KB [k][c]
    int tid = threadIdx.x;
    for (int i = tid; i < HID_C * OUT_C / 4; i += 256)
        ((float4*)w2lds)[i] = ((const float4*)W2)[i];
    __syncthreads();
    int lane = tid & 63;
    int v = blockIdx.x * 4 + (tid >> 6);
    int start = row_ptr[v];
    int cnt = deg[v];
    float acc0 = xw1s[(size_t)v * HID_C + lane];   // self-loop term (already dis-scaled)
    float acc1 = 0.f, acc2 = 0.f, acc3 = 0.f;
    for (int base = 0; base < cnt; base += 64) {
        int mcnt = min(64, cnt - base);
        int sj = 0;
        if (lane < mcnt) sj = csr_src[start + base + lane];
        int j = 0;
        for (; j + 8 <= mcnt; j += 8) {
            int s0 = __shfl(sj, j + 0), s1 = __shfl(sj, j + 1);
            int s2 = __shfl(sj, j + 2), s3 = __shfl(sj, j + 3);
            int s4 = __shfl(sj, j + 4), s5 = __shfl(sj, j + 5);
            int s6 = __shfl(sj, j + 6), s7 = __shfl(sj, j + 7);
            float v0 = xw1s[(size_t)s0 * HID_C + lane];
            float v1 = xw1s[(size_t)s1 * HID_C + lane];
            float v2 = xw1s[(size_t)s2 * HID_C + lane];
            float v3 = xw1s[(size_t)s3 * HID_C + lane];
            float v4 = xw1s[(size_t)s4 * HID_C + lane];
            float v5 = xw1s[(size_t)s5 * HID_C + lane];
            float v6 = xw1s[(size_t)s6 * HID_C + lane];
            float v7 = xw1s[(size_t)s7 * HID_C + lane];
            acc0 += v0 + v4;
            acc1 += v1 + v5;
            acc2 += v2 + v6;
            acc3 += v3 + v7;
        }
        for (; j < mcnt; ++j) {
            int s = __shfl(sj, j);
            acc0 += xw1s[(size_t)s * HID_C + lane];
        }
    }
    float dv = dis[v];
    float o = fmaf(dv, (acc0 + acc1) + (acc2 + acc3), b1[lane]);
    float hval = fmaxf(o, 0.f);                    // ReLU fused; h stays in-register

    // fused mm2: lane = (c, khalf); khalf sums k in [32*half, 32*half+32)
    int c = lane & 31;
    int hf = lane & 32;                            // 0 or 32
    float s = 0.f;
#pragma unroll
    for (int k0 = 0; k0 < 32; ++k0) {
        float hk = __shfl(hval, k0 | hf);          // broadcast h[k] across the half
        s = fmaf(hk, w2lds[((k0 | hf) << 5) + c], s);
    }
    s += __shfl_xor(s, 32);                        // merge the two k-halves
    if (lane < 32)
        xw2s[(size_t)v * OUT_C + c] = s * dv;
}

// layer-2 aggregation: 32-lane group per node; dis folded; 8 gather loads in flight.
__global__ __launch_bounds__(256) void k_agg2(const float* __restrict__ xw2s, const int* __restrict__ csr_src,
                                              const int* __restrict__ row_ptr, const int* __restrict__ deg,
                                              const float* __restrict__ dis, const float* __restrict__ b2,
                                              float* __restrict__ out2) {
    int lane = threadIdx.x & 31;
    int v = blockIdx.x * 8 + (threadIdx.x >> 5);
    int start = row_ptr[v];
    int cnt = deg[v];
    float acc0 = xw2s[(size_t)v * OUT_C + lane];   // self-loop term
    float acc1 = 0.f, acc2 = 0.f, acc3 = 0.f;
    for (int base = 0; base < cnt; base += 32) {
        int mcnt = min(32, cnt - base);
        int sj = 0;
        if (lane < mcnt) sj = csr_src[start + base + lane];
        int j = 0;
        for (; j + 8 <= mcnt; j += 8) {
            int s0 = __shfl(sj, j + 0, 32), s1 = __shfl(sj, j + 1, 32);
            int s2 = __shfl(sj, j + 2, 32), s3 = __shfl(sj, j + 3, 32);
            int s4 = __shfl(sj, j + 4, 32), s5 = __shfl(sj, j + 5, 32);
            int s6 = __shfl(sj, j + 6, 32), s7 = __shfl(sj, j + 7, 32);
            float v0 = xw2s[(size_t)s0 * OUT_C + lane];
            float v1 = xw2s[(size_t)s1 * OUT_C + lane];
            float v2 = xw2s[(size_t)s2 * OUT_C + lane];
            float v3 = xw2s[(size_t)s3 * OUT_C + lane];
            float v4 = xw2s[(size_t)s4 * OUT_C + lane];
            float v5 = xw2s[(size_t)s5 * OUT_C + lane];
            float v6 = xw2s[(size_t)s6 * OUT_C + lane];
            float v7 = xw2s[(size_t)s7 * OUT_C + lane];
            acc0 += v0 + v4;
            acc1 += v1 + v5;
            acc2 += v2 + v6;
            acc3 += v3 + v7;
        }
        for (; j < mcnt; ++j) {
            int s = __shfl(sj, j, 32);
            acc0 += xw2s[(size_t)s * OUT_C + lane];
        }
    }
    out2[(size_t)v * OUT_C + lane] = fmaf(dis[v], (acc0 + acc1) + (acc2 + acc3), b2[lane]);
}

// per-graph top-30 by channel 31 (desc, stable), emit [512, 30*32] f32.
__global__ __launch_bounds__(256) void k_sort(const float* __restrict__ out2, float* __restrict__ out) {
    __shared__ float keys[NPG];
    __shared__ int order[TOPK];
    int g = blockIdx.x;
    int tid = threadIdx.x;
    int base = g * NPG;
    if (tid < NPG) keys[tid] = out2[(size_t)(base + tid) * OUT_C + (OUT_C - 1)];
    __syncthreads();
    if (tid < NPG) {
        float my = keys[tid];
        int r = 0;
        for (int j = 0; j < NPG; ++j) {
            float kj = keys[j];
            r += (kj > my) || (kj == my && j < tid);
        }
        if (r < TOPK) order[r] = tid;
    }
    __syncthreads();
    for (int idx = tid; idx < TOPK * OUT_C; idx += 256) {
        int r = idx >> 5;
        int c = idx & 31;
        int n = order[r];
        out[g * (TOPK * OUT_C) + idx] = out2[(size_t)(base + n) * OUT_C + c];
    }
}

extern "C" void kernel_launch(void* const* d_in, const int* in_sizes, int n_in,
                              void* d_out, int out_size, void* d_ws, size_t ws_size,
                              hipStream_t stream) {
    const float* x  = (const float*)d_in[0];
    const int*   ei = (const int*)d_in[1];
    const int*   srcp = ei;             // edge_index[0]
    const int*   dstp = ei + N_EDGES;   // edge_index[1]
    // d_in[2] (batch) unused: graphs are contiguous 196-node blocks.
    const float* W1 = (const float*)d_in[3];
    const float* b1 = (const float*)d_in[4];
    const float* W2 = (const float*)d_in[5];
    const float* b2 = (const float*)d_in[6];
    float* out = (float*)d_out;

    char* w = (char*)d_ws;
    int*    deg      = (int*)(w + OFF_DEG);
    int*    row_ptr  = (int*)(w + OFF_ROWPTR);
    float*  dis      = (float*)(w + OFF_DIS);
    int*    bcnt     = (int*)(w + OFF_BCNT);
    int*    bbase    = (int*)(w + OFF_BBASE);
    int*    arena    = (int*)(w + OFF_ARENA);
    int*    csr_src  = (int*)(w + OFF_CSR);
    float*  xw1s     = (float*)(w + OFF_XW1);
    float*  xw2s     = (float*)(w + OFF_XW2);
    float*  out2     = (float*)(w + OFF_OUT2);   // aliases arena slot (dead after k_build)

    hipMemsetAsync(bcnt, 0, NB * sizeof(int), stream);
    k_bucket<<<N_EDGES / (256 * 8), 256, 0, stream>>>(srcp, dstp, bcnt, arena);
    k_bscan <<<1, 256, 0, stream>>>(bcnt, bbase);
    k_build <<<NB, 256, 0, stream>>>(arena, bcnt, bbase, row_ptr, deg, dis, csr_src);
    k_mm1   <<<N_NODES / 64, 256, 0, stream>>>(x, W1, dis, xw1s);
    k_agg1  <<<N_NODES / 4, 256, 0, stream>>>(xw1s, csr_src, row_ptr, deg, dis, b1, W2, xw2s);
    k_agg2  <<<N_NODES / 8, 256, 0, stream>>>(xw2s, csr_src, row_ptr, deg, dis, b2, out2);
    k_sort  <<<NUM_GRAPHS, 256, 0, stream>>>(out2, out);
}

// Round 12
// 220.710 us; speedup vs baseline: 2.0924x; 1.0261x over previous
//
#include <hip/hip_runtime.h>

#define N_NODES   100352
#define N_EDGES   1605632
#define IN_C      128
#define HID_C     64
#define OUT_C     32
#define NUM_GRAPHS 512
#define NPG       196
#define TOPK      30

#define NB        196     // buckets = dst>>9 (512 nodes each; 196*512 = 100352)
#define BCAP      10240   // arena capacity per bucket (E[nb]=8192, sigma~90)
#define LCAP      10240   // LDS staging capacity in k_build (40 KB)

typedef float v16f __attribute__((ext_vector_type(16)));

// ws layout (bytes)
#define OFF_DEG     0u          // int[N]
#define OFF_ROWPTR  401408u     // int[N]
#define OFF_DIS     802816u     // float[N]
#define OFF_BCNT    1204224u    // int[NB]
#define OFF_ARENA   1206272u    // int[NB*BCAP] = 8,028,160 B (packed; dead after k_build)
#define OFF_OUT2    1206272u    // float[N*32] = 12,845,056 B -- aliases arena region (16 MB reserved)
#define OFF_CSR     17262592u   // int[E]
#define OFF_XW1     23685120u   // float[N*64]  (dis-scaled)
#define OFF_H       49375232u   // float[N*64]
#define OFF_XW2     75065344u   // float[N*32]  (dis-scaled)

// Pass 1: bucketize edges, packed (src<<9 | dst&511) -- src < 2^17.
__global__ __launch_bounds__(256) void k_bucket(const int* __restrict__ src, const int* __restrict__ dst,
                                                int* __restrict__ bucket_cnt, int* __restrict__ arena) {
    __shared__ int hist[NB];
    __shared__ int cur[NB];
    int tid = threadIdx.x;
    for (int i = tid; i < NB; i += 256) hist[i] = 0;
    __syncthreads();
    int e0 = (blockIdx.x * 256 + tid) * 8;       // 8 edges per thread
    int4 sa = ((const int4*)src)[e0 / 4], sb = ((const int4*)src)[e0 / 4 + 1];
    int4 da = ((const int4*)dst)[e0 / 4], db = ((const int4*)dst)[e0 / 4 + 1];
    int es[8] = {sa.x, sa.y, sa.z, sa.w, sb.x, sb.y, sb.z, sb.w};
    int ed[8] = {da.x, da.y, da.z, da.w, db.x, db.y, db.z, db.w};
    int eb[8];
#pragma unroll
    for (int j = 0; j < 8; ++j) { eb[j] = ed[j] >> 9; atomicAdd(&hist[eb[j]], 1); }
    __syncthreads();
    for (int i = tid; i < NB; i += 256) {
        int c = hist[i];
        cur[i] = (c > 0) ? atomicAdd(&bucket_cnt[i], c) : 0;
    }
    __syncthreads();
#pragma unroll
    for (int j = 0; j < 8; ++j) {
        int p = atomicAdd(&cur[eb[j]], 1);
        if (p < BCAP) arena[(size_t)eb[j] * BCAP + p] = (es[j] << 9) | (ed[j] & 511);
    }
}

// Pass 2: per bucket (512 nodes). Preamble scans all 196 bucket counts in-block
// (replaces the k_bscan launch); then deg/row_ptr/dis via LDS, CSR via LDS staging.
__global__ __launch_bounds__(256) void k_build(const int* __restrict__ arena, const int* __restrict__ bucket_cnt,
                                               int* __restrict__ row_ptr,
                                               int* __restrict__ deg, float* __restrict__ dis,
                                               int* __restrict__ csr_src) {
    __shared__ int bsc[256];
    __shared__ int dloc[512];
    __shared__ int sc[512];
    __shared__ int cur[512];
    __shared__ int stage[LCAP];
    int b = blockIdx.x;
    int tid = threadIdx.x;
    // in-block exclusive scan of the 196 bucket counts -> this block's base
    int bv = (tid < NB) ? bucket_cnt[tid] : 0;
    bsc[tid] = bv;
    __syncthreads();
    for (int o = 1; o < 256; o <<= 1) {
        int a = (tid >= o) ? bsc[tid - o] : 0;
        __syncthreads();
        bsc[tid] += a;
        __syncthreads();
    }
    int nb = min(bucket_cnt[b], BCAP);
    int gbase = bsc[b] - bucket_cnt[b];            // exclusive prefix for bucket b
    const int* ap = arena + (size_t)b * BCAP;
    for (int i = tid; i < 512; i += 256) dloc[i] = 0;
    __syncthreads();
    for (int i = tid; i < nb; i += 256) {
        int e = ap[i];
        atomicAdd(&dloc[e & 511], 1);
    }
    __syncthreads();
    for (int i = tid; i < 512; i += 256) sc[i] = dloc[i];
    __syncthreads();
    for (int o = 1; o < 512; o <<= 1) {        // Hillis-Steele inclusive scan, 512 elems
        int i0 = tid, i1 = tid + 256;
        int v0 = (i0 >= o) ? sc[i0 - o] : 0;
        int v1 = (i1 >= o) ? sc[i1 - o] : 0;
        __syncthreads();
        sc[i0] += v0;
        sc[i1] += v1;
        __syncthreads();
    }
    for (int i = tid; i < 512; i += 256) {
        int d = dloc[i];
        int off = sc[i] - d;                   // exclusive prefix
        int node = b * 512 + i;
        row_ptr[node] = gbase + off;
        deg[node] = d;
        dis[node] = (float)(1.0 / sqrt((double)(d + 1)));   // +1 self-loop
        cur[i] = off;
    }
    __syncthreads();
    bool inlds = (nb <= LCAP);
    for (int i = tid; i < nb; i += 256) {
        int e = ap[i];
        int p = atomicAdd(&cur[e & 511], 1);
        int sv = ((unsigned)e) >> 9;
        if (inlds) stage[p] = sv;
        else       csr_src[gbase + p] = sv;
    }
    __syncthreads();
    if (inlds)
        for (int i = tid; i < nb; i += 256) csr_src[gbase + i] = stage[i];
}

// xw1s = dis[n] * (x @ W1). One node per thread, COL-SPLIT 4-way:
// block = 64 nodes x 4 col-quarters; ch wave-uniform -> readfirstlane -> SGPR.
// Per q: 4 batched s_load_dwordx16 (one per k row), ONE drain, 64 FMAs.
__global__ __launch_bounds__(256) void k_mm1(const float* __restrict__ x, const float* __restrict__ W1,
                                             const float* __restrict__ dis, float* __restrict__ xw1s) {
    int tid = threadIdx.x;
    int n = blockIdx.x * 64 + (tid & 63);
    int ch = __builtin_amdgcn_readfirstlane((tid >> 6) * 16);   // col quarter -> SGPR
    const float4* xrow = (const float4*)(x + (size_t)n * IN_C);
    float acc[16];
#pragma unroll
    for (int c = 0; c < 16; ++c) acc[c] = 0.f;
    float4 xq = xrow[0];
#pragma unroll 1
    for (int q = 0; q < IN_C / 4; ++q) {
        float4 xn = xrow[(q + 1) & (IN_C / 4 - 1)];   // prefetch next chunk
        const float* wp = W1 + q * 4 * HID_C + ch;    // scalar address chain
        v16f w0, w1, w2, w3;
        asm volatile("s_load_dwordx16 %0, %1, 0x0"   : "=s"(w0) : "s"(wp));
        asm volatile("s_load_dwordx16 %0, %1, 0x100" : "=s"(w1) : "s"(wp));
        asm volatile("s_load_dwordx16 %0, %1, 0x200" : "=s"(w2) : "s"(wp));
        asm volatile("s_load_dwordx16 %0, %1, 0x300" : "=s"(w3) : "s"(wp));
        asm volatile("s_waitcnt lgkmcnt(0)" : "+s"(w0), "+s"(w1), "+s"(w2), "+s"(w3));
#pragma unroll
        for (int c = 0; c < 16; ++c) {
            acc[c] = fmaf(xq.x, w0[c], acc[c]);
            acc[c] = fmaf(xq.y, w1[c], acc[c]);
            acc[c] = fmaf(xq.z, w2[c], acc[c]);
            acc[c] = fmaf(xq.w, w3[c], acc[c]);
        }
        xq = xn;
    }
    float dv = dis[n];
    float4* orow = (float4*)(xw1s + (size_t)n * HID_C + ch);
#pragma unroll
    for (int c4 = 0; c4 < 4; ++c4) {
        float4 o;
        o.x = acc[4 * c4 + 0] * dv;
        o.y = acc[4 * c4 + 1] * dv;
        o.z = acc[4 * c4 + 2] * dv;
        o.w = acc[4 * c4 + 3] * dv;
        orow[c4] = o;
    }
}

// layer-1 aggregation (UNFUSED, lean): one 64-lane wave per node; dis folded;
// 8 gather loads in flight. Near the random-gather pattern floor (192 MB FETCH).
__global__ __launch_bounds__(256) void k_agg1(const float* __restrict__ xw1s, const int* __restrict__ csr_src,
                                              const int* __restrict__ row_ptr, const int* __restrict__ deg,
                                              const float* __restrict__ dis, const float* __restrict__ b1,
                                              float* __restrict__ h) {
    int lane = threadIdx.x & 63;
    int v = blockIdx.x * 4 + (threadIdx.x >> 6);
    int start = row_ptr[v];
    int cnt = deg[v];
    float acc0 = xw1s[(size_t)v * HID_C + lane];   // self-loop term (already dis-scaled)
    float acc1 = 0.f, acc2 = 0.f, acc3 = 0.f;
    for (int base = 0; base < cnt; base += 64) {
        int mcnt = min(64, cnt - base);
        int sj = 0;
        if (lane < mcnt) sj = csr_src[start + base + lane];
        int j = 0;
        for (; j + 8 <= mcnt; j += 8) {
            int s0 = __shfl(sj, j + 0), s1 = __shfl(sj, j + 1);
            int s2 = __shfl(sj, j + 2), s3 = __shfl(sj, j + 3);
            int s4 = __shfl(sj, j + 4), s5 = __shfl(sj, j + 5);
            int s6 = __shfl(sj, j + 6), s7 = __shfl(sj, j + 7);
            float v0 = xw1s[(size_t)s0 * HID_C + lane];
            float v1 = xw1s[(size_t)s1 * HID_C + lane];
            float v2 = xw1s[(size_t)s2 * HID_C + lane];
            float v3 = xw1s[(size_t)s3 * HID_C + lane];
            float v4 = xw1s[(size_t)s4 * HID_C + lane];
            float v5 = xw1s[(size_t)s5 * HID_C + lane];
            float v6 = xw1s[(size_t)s6 * HID_C + lane];
            float v7 = xw1s[(size_t)s7 * HID_C + lane];
            acc0 += v0 + v4;
            acc1 += v1 + v5;
            acc2 += v2 + v6;
            acc3 += v3 + v7;
        }
        for (; j < mcnt; ++j) {
            int s = __shfl(sj, j);
            acc0 += xw1s[(size_t)s * HID_C + lane];
        }
    }
    float o = fmaf(dis[v], (acc0 + acc1) + (acc2 + acc3), b1[lane]);
    h[(size_t)v * HID_C + lane] = fmaxf(o, 0.f);   // ReLU fused
}

// xw2s = dis[n] * (h @ W2). One node per thread, col-split 2-way (16 cols each).
__global__ __launch_bounds__(256) void k_mm2(const float* __restrict__ h, const float* __restrict__ W2,
                                             const float* __restrict__ dis, float* __restrict__ xw2s) {
    int tid = threadIdx.x;
    int n = blockIdx.x * 128 + (tid & 127);
    int ch = __builtin_amdgcn_readfirstlane((tid >> 7) * 16);   // wave-uniform col half -> SGPR
    const float4* hrow = (const float4*)(h + (size_t)n * HID_C);
    float acc[16];
#pragma unroll
    for (int c = 0; c < 16; ++c) acc[c] = 0.f;
    float4 xq = hrow[0];
#pragma unroll 1
    for (int q = 0; q < HID_C / 4; ++q) {
        float4 xn = hrow[(q + 1) & (HID_C / 4 - 1)];
        const float* wp = W2 + q * 4 * OUT_C + ch;
        v16f w0, w1, w2, w3;
        asm volatile("s_load_dwordx16 %0, %1, 0x0"   : "=s"(w0) : "s"(wp));
        asm volatile("s_load_dwordx16 %0, %1, 0x80"  : "=s"(w1) : "s"(wp));
        asm volatile("s_load_dwordx16 %0, %1, 0x100" : "=s"(w2) : "s"(wp));
        asm volatile("s_load_dwordx16 %0, %1, 0x180" : "=s"(w3) : "s"(wp));
        asm volatile("s_waitcnt lgkmcnt(0)" : "+s"(w0), "+s"(w1), "+s"(w2), "+s"(w3));
#pragma unroll
        for (int c = 0; c < 16; ++c) {
            acc[c] = fmaf(xq.x, w0[c], acc[c]);
            acc[c] = fmaf(xq.y, w1[c], acc[c]);
            acc[c] = fmaf(xq.z, w2[c], acc[c]);
            acc[c] = fmaf(xq.w, w3[c], acc[c]);
        }
        xq = xn;
    }
    float dv = dis[n];
    float4* orow = (float4*)(xw2s + (size_t)n * OUT_C + ch);
#pragma unroll
    for (int c4 = 0; c4 < 4; ++c4) {
        float4 o;
        o.x = acc[4 * c4 + 0] * dv;
        o.y = acc[4 * c4 + 1] * dv;
        o.z = acc[4 * c4 + 2] * dv;
        o.w = acc[4 * c4 + 3] * dv;
        orow[c4] = o;
    }
}

// layer-2 aggregation: 32-lane group per node; dis folded; 8 gather loads in flight.
__global__ __launch_bounds__(256) void k_agg2(const float* __restrict__ xw2s, const int* __restrict__ csr_src,
                                              const int* __restrict__ row_ptr, const int* __restrict__ deg,
                                              const float* __restrict__ dis, const float* __restrict__ b2,
                                              float* __restrict__ out2) {
    int lane = threadIdx.x & 31;
    int v = blockIdx.x * 8 + (threadIdx.x >> 5);
    int start = row_ptr[v];
    int cnt = deg[v];
    float acc0 = xw2s[(size_t)v * OUT_C + lane];   // self-loop term
    float acc1 = 0.f, acc2 = 0.f, acc3 = 0.f;
    for (int base = 0; base < cnt; base += 32) {
        int mcnt = min(32, cnt - base);
        int sj = 0;
        if (lane < mcnt) sj = csr_src[start + base + lane];
        int j = 0;
        for (; j + 8 <= mcnt; j += 8) {
            int s0 = __shfl(sj, j + 0, 32), s1 = __shfl(sj, j + 1, 32);
            int s2 = __shfl(sj, j + 2, 32), s3 = __shfl(sj, j + 3, 32);
            int s4 = __shfl(sj, j + 4, 32), s5 = __shfl(sj, j + 5, 32);
            int s6 = __shfl(sj, j + 6, 32), s7 = __shfl(sj, j + 7, 32);
            float v0 = xw2s[(size_t)s0 * OUT_C + lane];
            float v1 = xw2s[(size_t)s1 * OUT_C + lane];
            float v2 = xw2s[(size_t)s2 * OUT_C + lane];
            float v3 = xw2s[(size_t)s3 * OUT_C + lane];
            float v4 = xw2s[(size_t)s4 * OUT_C + lane];
            float v5 = xw2s[(size_t)s5 * OUT_C + lane];
            float v6 = xw2s[(size_t)s6 * OUT_C + lane];
            float v7 = xw2s[(size_t)s7 * OUT_C + lane];
            acc0 += v0 + v4;
            acc1 += v1 + v5;
            acc2 += v2 + v6;
            acc3 += v3 + v7;
        }
        for (; j < mcnt; ++j) {
            int s = __shfl(sj, j, 32);
            acc0 += xw2s[(size_t)s * OUT_C + lane];
        }
    }
    out2[(size_t)v * OUT_C + lane] = fmaf(dis[v], (acc0 + acc1) + (acc2 + acc3), b2[lane]);
}

// per-graph top-30 by channel 31 (desc, stable), emit [512, 30*32] f32.
__global__ __launch_bounds__(256) void k_sort(const float* __restrict__ out2, float* __restrict__ out) {
    __shared__ float keys[NPG];
    __shared__ int order[TOPK];
    int g = blockIdx.x;
    int tid = threadIdx.x;
    int base = g * NPG;
    if (tid < NPG) keys[tid] = out2[(size_t)(base + tid) * OUT_C + (OUT_C - 1)];
    __syncthreads();
    if (tid < NPG) {
        float my = keys[tid];
        int r = 0;
        for (int j = 0; j < NPG; ++j) {
            float kj = keys[j];
            r += (kj > my) || (kj == my && j < tid);
        }
        if (r < TOPK) order[r] = tid;
    }
    __syncthreads();
    for (int idx = tid; idx < TOPK * OUT_C; idx += 256) {
        int r = idx >> 5;
        int c = idx & 31;
        int n = order[r];
        out[g * (TOPK * OUT_C) + idx] = out2[(size_t)(base + n) * OUT_C + c];
    }
}

extern "C" void kernel_launch(void* const* d_in, const int* in_sizes, int n_in,
                              void* d_out, int out_size, void* d_ws, size_t ws_size,
                              hipStream_t stream) {
    const float* x  = (const float*)d_in[0];
    const int*   ei = (const int*)d_in[1];
    const int*   srcp = ei;             // edge_index[0]
    const int*   dstp = ei + N_EDGES;   // edge_index[1]
    // d_in[2] (batch) unused: graphs are contiguous 196-node blocks.
    const float* W1 = (const float*)d_in[3];
    const float* b1 = (const float*)d_in[4];
    const float* W2 = (const float*)d_in[5];
    const float* b2 = (const float*)d_in[6];
    float* out = (float*)d_out;

    char* w = (char*)d_ws;
    int*    deg      = (int*)(w + OFF_DEG);
    int*    row_ptr  = (int*)(w + OFF_ROWPTR);
    float*  dis      = (float*)(w + OFF_DIS);
    int*    bcnt     = (int*)(w + OFF_BCNT);
    int*    arena    = (int*)(w + OFF_ARENA);
    int*    csr_src  = (int*)(w + OFF_CSR);
    float*  xw1s     = (float*)(w + OFF_XW1);
    float*  h        = (float*)(w + OFF_H);
    float*  xw2s     = (float*)(w + OFF_XW2);
    float*  out2     = (float*)(w + OFF_OUT2);   // aliases arena region (dead after k_build)

    hipMemsetAsync(bcnt, 0, NB * sizeof(int), stream);
    k_bucket<<<N_EDGES / (256 * 8), 256, 0, stream>>>(srcp, dstp, bcnt, arena);
    k_build <<<NB, 256, 0, stream>>>(arena, bcnt, row_ptr, deg, dis, csr_src);
    k_mm1   <<<N_NODES / 64, 256, 0, stream>>>(x, W1, dis, xw1s);
    k_agg1  <<<N_NODES / 4, 256, 0, stream>>>(xw1s, csr_src, row_ptr, deg, dis, b1, h);
    k_mm2   <<<N_NODES / 128, 256, 0, stream>>>(h, W2, dis, xw2s);
    k_agg2  <<<N_NODES / 8, 256, 0, stream>>>(xw2s, csr_src, row_ptr, deg, dis, b2, out2);
    k_sort  <<<NUM_GRAPHS, 256, 0, stream>>>(out2, out);
}